// Round 1
// baseline (561.842 us; speedup 1.0000x reference)
//
#include <hip/hip_runtime.h>
#include <stdint.h>

#define AS1 __attribute__((address_space(1)))
#define AS3 __attribute__((address_space(3)))

typedef __attribute__((ext_vector_type(8))) short bf16x8;   // 8 bf16 = 4 VGPRs
typedef __attribute__((ext_vector_type(4))) float f32x4;

#define NB 8
#define NT 1024
#define NE 1024
#define NH 16
#define BT (NB * NT)

__device__ __forceinline__ unsigned short f2bf(float f) {
    unsigned int u = __builtin_bit_cast(unsigned int, f);
    u += 0x7FFFu + ((u >> 16) & 1u);          // RNE
    return (unsigned short)(u >> 16);
}

// ---------------- f32 -> bf16 conversion (n % 4 == 0) ----------------
__global__ void k_cvt(const float* __restrict__ in, unsigned short* __restrict__ out, int n) {
    int i = (blockIdx.x * 256 + threadIdx.x) * 4;
    if (i >= n) return;
    float4 f = *reinterpret_cast<const float4*>(in + i);
    ushort4 o;
    o.x = f2bf(f.x); o.y = f2bf(f.y); o.z = f2bf(f.z); o.w = f2bf(f.w);
    *reinterpret_cast<ushort4*>(out + i) = o;
}

// ---------------- GEMM: C[m,n] = (sum_k A[m,k]*W[g,n,k] + bias[g,n]) * scale ----
// A: [8192 x 1024] bf16 row-major. W: [G?,1024,1024] bf16 (K contiguous).
// rt != nullptr selects per-batch expert g = rt[m0/T]; else g = 0.
#define BM 128
#define BN 128
#define BK 32

template <bool OUT_F32>
__global__ void k_gemm(const unsigned short* __restrict__ A,
                       const unsigned short* __restrict__ W,
                       const float* __restrict__ bias,
                       const int* __restrict__ rt,
                       void* __restrict__ Cout,
                       float scale)
{
    __shared__ __attribute__((aligned(16))) unsigned short As[BM * BK];
    __shared__ __attribute__((aligned(16))) unsigned short Bs[BN * BK];
    const int tid  = threadIdx.x;
    const int wid  = tid >> 6;
    const int lane = tid & 63;
    const int m0 = blockIdx.y * BM;
    const int n0 = blockIdx.x * BN;
    int g = 0;
    if (rt) g = rt[m0 / NT];
    const unsigned short* Wg = W + (size_t)g * NE * NE;
    const float* biasg = bias + (size_t)g * NE;

    const int wr = (wid >> 1) * 64;
    const int wc = (wid & 1) * 64;
    const int frow = lane & 15;
    const int fk8  = (lane >> 4) * 8;

    f32x4 acc[4][4];
#pragma unroll
    for (int m = 0; m < 4; ++m)
#pragma unroll
        for (int n = 0; n < 4; ++n) acc[m][n] = (f32x4){0.f, 0.f, 0.f, 0.f};

    const int c0 = wid * 2;   // this wave's two 1KB staging issues per tile
    for (int k0 = 0; k0 < NE; k0 += BK) {
#pragma unroll
        for (int i = 0; i < 2; ++i) {
            int ci  = (c0 + i) * 64 + lane;      // 16B chunk id in [0,512)
            int row = ci >> 2;                   // 4 chunks per 64B row
            int kc  = (ci & 3) * 8;
            const unsigned short* srcA = A  + (size_t)(m0 + row) * NE + k0 + kc;
            const unsigned short* srcB = Wg + (size_t)(n0 + row) * NE + k0 + kc;
            __builtin_amdgcn_global_load_lds((AS1 void*)srcA, (AS3 void*)(As + (c0 + i) * 512), 16, 0, 0);
            __builtin_amdgcn_global_load_lds((AS1 void*)srcB, (AS3 void*)(Bs + (c0 + i) * 512), 16, 0, 0);
        }
        __syncthreads();   // drains vmcnt (LDS valid) + wave sync
        bf16x8 af[4], bfr[4];
#pragma unroll
        for (int m = 0; m < 4; ++m)
            af[m] = *reinterpret_cast<const bf16x8*>(As + (wr + m * 16 + frow) * BK + fk8);
#pragma unroll
        for (int n = 0; n < 4; ++n)
            bfr[n] = *reinterpret_cast<const bf16x8*>(Bs + (wc + n * 16 + frow) * BK + fk8);
#pragma unroll
        for (int m = 0; m < 4; ++m)
#pragma unroll
            for (int n = 0; n < 4; ++n)
                acc[m][n] = __builtin_amdgcn_mfma_f32_16x16x32_bf16(af[m], bfr[n], acc[m][n], 0, 0, 0);
        __syncthreads();   // all reads done before next stage overwrites
    }

#pragma unroll
    for (int m = 0; m < 4; ++m) {
        int row = m0 + wr + m * 16 + (lane >> 4) * 4;
#pragma unroll
        for (int n = 0; n < 4; ++n) {
            int col = n0 + wc + n * 16 + frow;
            float bv = biasg[col];
            f32x4 v = acc[m][n];
#pragma unroll
            for (int r = 0; r < 4; ++r) {
                float val = (v[r] + bv) * scale;
                if (OUT_F32)
                    ((float*)Cout)[(size_t)(row + r) * NE + col] = val;
                else
                    ((unsigned short*)Cout)[(size_t)(row + r) * NE + col] = f2bf(val);
            }
        }
    }
}

// ---------------- V transpose: Vt[(b,h),d,s] = V[b,s,h*64+d] ----------------
__global__ void k_vtrans(const unsigned short* __restrict__ V, unsigned short* __restrict__ Vt) {
    __shared__ unsigned short tile[64][65];
    const int blk = blockIdx.x;
    const int bh = blk >> 4;
    const int b = bh >> 4;
    const int h = bh & 15;
    const int s0 = (blk & 15) * 64;
    const int tid = threadIdx.x;
#pragma unroll
    for (int i = 0; i < 2; ++i) {
        int seg = tid + i * 256;
        int row = seg >> 3;
        int c8 = (seg & 7) * 8;
        const unsigned short* src = V + (size_t)(b * NT + s0 + row) * NE + h * 64 + c8;
        ushort4 u0 = *reinterpret_cast<const ushort4*>(src);
        ushort4 u1 = *reinterpret_cast<const ushort4*>(src + 4);
        tile[row][c8 + 0] = u0.x; tile[row][c8 + 1] = u0.y;
        tile[row][c8 + 2] = u0.z; tile[row][c8 + 3] = u0.w;
        tile[row][c8 + 4] = u1.x; tile[row][c8 + 5] = u1.y;
        tile[row][c8 + 6] = u1.z; tile[row][c8 + 7] = u1.w;
    }
    __syncthreads();
#pragma unroll
    for (int i = 0; i < 2; ++i) {
        int seg = tid + i * 256;
        int drow = seg >> 3;
        int s8 = (seg & 7) * 8;
        ushort4 u0, u1;
        u0.x = tile[s8 + 0][drow]; u0.y = tile[s8 + 1][drow];
        u0.z = tile[s8 + 2][drow]; u0.w = tile[s8 + 3][drow];
        u1.x = tile[s8 + 4][drow]; u1.y = tile[s8 + 5][drow];
        u1.z = tile[s8 + 6][drow]; u1.w = tile[s8 + 7][drow];
        unsigned short* dst = Vt + (size_t)(bh * 64 + drow) * NT + s0 + s8;
        *reinterpret_cast<ushort4*>(dst) = u0;
        *reinterpret_cast<ushort4*>(dst + 4) = u1;
    }
}

// ---------------- fused dual-stream flash attention ----------------
// 1 block = (b,h, 64 q-rows); 1 wave = 16 q-rows. KVBLK=32.
// attn = 0.45 * softmax(Q Kt) V + 0.05 * softmax(Qr Krt) V
__global__ void k_attn(const unsigned short* __restrict__ Q,
                       const unsigned short* __restrict__ K,
                       const unsigned short* __restrict__ Qr,
                       const unsigned short* __restrict__ Kr,
                       const unsigned short* __restrict__ Vt,
                       unsigned short* __restrict__ attnO)
{
    __shared__ __attribute__((aligned(16))) unsigned short Ps[4][512];  // per-wave 16x32 P tile
    const int blk = blockIdx.x;
    const int tile16 = blk & 15;
    const int bh = blk >> 4;
    const int b = bh >> 4;
    const int h = bh & 15;
    const int wid = threadIdx.x >> 6;
    const int lane = threadIdx.x & 63;
    const int frow = lane & 15;
    const int fk8 = (lane >> 4) * 8;
    const int t0 = tile16 * 64 + wid * 16;

    const size_t qoff = (size_t)(b * NT + t0 + frow) * NE + h * 64;
    const bf16x8 qf0 = *reinterpret_cast<const bf16x8*>(Q + qoff + fk8);
    const bf16x8 qf1 = *reinterpret_cast<const bf16x8*>(Q + qoff + 32 + fk8);
    const bf16x8 qr0 = *reinterpret_cast<const bf16x8*>(Qr + qoff + fk8);
    const bf16x8 qr1 = *reinterpret_cast<const bf16x8*>(Qr + qoff + 32 + fk8);

    const unsigned short* Kb  = K  + (size_t)b * NT * NE + h * 64;
    const unsigned short* Krb = Kr + (size_t)b * NT * NE + h * 64;
    const unsigned short* Vtb = Vt + (size_t)bh * 64 * NT;
    unsigned short* Pw = &Ps[wid][0];

    f32x4 og[4], orr[4];
    float mg[4], lg[4], mr[4], lr[4];
#pragma unroll
    for (int i = 0; i < 4; ++i) {
        og[i] = (f32x4){0.f, 0.f, 0.f, 0.f};
        orr[i] = (f32x4){0.f, 0.f, 0.f, 0.f};
        mg[i] = -1e30f; lg[i] = 0.f; mr[i] = -1e30f; lr[i] = 0.f;
    }

    for (int s0 = 0; s0 < NT; s0 += 32) {
        f32x4 sg[2], sr[2];
#pragma unroll
        for (int nf = 0; nf < 2; ++nf) {
            const unsigned short* kp = Kb + (size_t)(s0 + nf * 16 + frow) * NE + fk8;
            bf16x8 ka = *reinterpret_cast<const bf16x8*>(kp);
            bf16x8 kb2 = *reinterpret_cast<const bf16x8*>(kp + 32);
            f32x4 z = (f32x4){0.f, 0.f, 0.f, 0.f};
            z = __builtin_amdgcn_mfma_f32_16x16x32_bf16(qf0, ka, z, 0, 0, 0);
            z = __builtin_amdgcn_mfma_f32_16x16x32_bf16(qf1, kb2, z, 0, 0, 0);
            sg[nf] = z;
            const unsigned short* kpr = Krb + (size_t)(s0 + nf * 16 + frow) * NE + fk8;
            bf16x8 kc = *reinterpret_cast<const bf16x8*>(kpr);
            bf16x8 kd = *reinterpret_cast<const bf16x8*>(kpr + 32);
            f32x4 z2 = (f32x4){0.f, 0.f, 0.f, 0.f};
            z2 = __builtin_amdgcn_mfma_f32_16x16x32_bf16(qr0, kc, z2, 0, 0, 0);
            z2 = __builtin_amdgcn_mfma_f32_16x16x32_bf16(qr1, kd, z2, 0, 0, 0);
            sr[nf] = z2;
        }
        bf16x8 vb[4];
#pragma unroll
        for (int nf2 = 0; nf2 < 4; ++nf2)
            vb[nf2] = *reinterpret_cast<const bf16x8*>(Vtb + (size_t)(nf2 * 16 + frow) * NT + s0 + fk8);

        auto update = [&](const f32x4* s, float* m, float* l, f32x4* o) {
            float rmax[4], rsum[4], p0[4], p1[4];
#pragma unroll
            for (int r = 0; r < 4; ++r) rmax[r] = fmaxf(s[0][r], s[1][r]);
#pragma unroll
            for (int off = 1; off <= 8; off <<= 1) {
#pragma unroll
                for (int r = 0; r < 4; ++r) rmax[r] = fmaxf(rmax[r], __shfl_xor(rmax[r], off));
            }
#pragma unroll
            for (int r = 0; r < 4; ++r) {
                float mnew = fmaxf(m[r], rmax[r]);
                float corr = __expf(m[r] - mnew);
                p0[r] = __expf(s[0][r] - mnew);
                p1[r] = __expf(s[1][r] - mnew);
                rsum[r] = p0[r] + p1[r];
                m[r] = mnew;
                l[r] *= corr;
#pragma unroll
                for (int nf2 = 0; nf2 < 4; ++nf2) o[nf2][r] *= corr;
            }
#pragma unroll
            for (int off = 1; off <= 8; off <<= 1) {
#pragma unroll
                for (int r = 0; r < 4; ++r) rsum[r] += __shfl_xor(rsum[r], off);
            }
#pragma unroll
            for (int r = 0; r < 4; ++r) {
                l[r] += rsum[r];
                int t = (lane >> 4) * 4 + r;
                Pw[t * 32 + frow] = f2bf(p0[r]);
                Pw[t * 32 + 16 + frow] = f2bf(p1[r]);
            }
            asm volatile("s_waitcnt lgkmcnt(0)" ::: "memory");  // cross-lane LDS P visibility (same wave)
            bf16x8 pa = *reinterpret_cast<const bf16x8*>(Pw + frow * 32 + fk8);
#pragma unroll
            for (int nf2 = 0; nf2 < 4; ++nf2)
                o[nf2] = __builtin_amdgcn_mfma_f32_16x16x32_bf16(pa, vb[nf2], o[nf2], 0, 0, 0);
        };
        update(sg, mg, lg, og);
        update(sr, mr, lr, orr);
    }

#pragma unroll
    for (int r = 0; r < 4; ++r) { mg[r] = 0.45f / lg[r]; mr[r] = 0.05f / lr[r]; }
#pragma unroll
    for (int nf2 = 0; nf2 < 4; ++nf2) {
#pragma unroll
        for (int r = 0; r < 4; ++r) {
            float val = og[nf2][r] * mg[r] + orr[nf2][r] * mr[r];
            int t = t0 + (lane >> 4) * 4 + r;
            attnO[(size_t)(b * NT + t) * NE + h * 64 + nf2 * 16 + frow] = f2bf(val);
        }
    }
}

// ---------------- launcher ----------------
extern "C" void kernel_launch(void* const* d_in, const int* in_sizes, int n_in,
                              void* d_out, int out_size, void* d_ws, size_t ws_size,
                              hipStream_t stream)
{
    const float* hs  = (const float*)d_in[0];
    const int*   rt  = (const int*)d_in[1];
    const float* Wq  = (const float*)d_in[2];
    const float* bq  = (const float*)d_in[3];
    const float* Wk  = (const float*)d_in[4];
    const float* bk  = (const float*)d_in[5];
    const float* Wv  = (const float*)d_in[6];
    const float* bv  = (const float*)d_in[7];
    const float* Wo  = (const float*)d_in[8];
    const float* bo  = (const float*)d_in[9];
    const float* RWq = (const float*)d_in[10];
    const float* Rbq = (const float*)d_in[11];
    const float* RWk = (const float*)d_in[12];
    const float* Rbk = (const float*)d_in[13];
    // RWv, Rbv (d_in[14], d_in[15]) are unused by the reference.

    unsigned short* w = (unsigned short*)d_ws;
    const size_t NBT = (size_t)BT * NE;   // 8M elems
    const size_t NW  = (size_t)NE * NE;   // 1M elems
    unsigned short* hsB  = w; w += NBT;
    unsigned short* Qb   = w; w += NBT;
    unsigned short* Kb   = w; w += NBT;
    unsigned short* Vb   = w; w += NBT;
    unsigned short* Qrb  = w; w += NBT;
    unsigned short* Krb  = w; w += NBT;
    unsigned short* Vtb  = w; w += NBT;
    unsigned short* atb  = w; w += NBT;
    unsigned short* WqB  = w; w += NW;
    unsigned short* WkB  = w; w += NW;
    unsigned short* WvB  = w; w += NW;
    unsigned short* WoB  = w; w += NW;
    unsigned short* RWqB = w; w += 4 * NW;
    unsigned short* RWkB = w; w += 4 * NW;

    k_cvt<<<dim3((unsigned)(NBT / 1024)), dim3(256), 0, stream>>>(hs, hsB, (int)NBT);
    k_cvt<<<dim3((unsigned)(NW / 1024)), dim3(256), 0, stream>>>(Wq, WqB, (int)NW);
    k_cvt<<<dim3((unsigned)(NW / 1024)), dim3(256), 0, stream>>>(Wk, WkB, (int)NW);
    k_cvt<<<dim3((unsigned)(NW / 1024)), dim3(256), 0, stream>>>(Wv, WvB, (int)NW);
    k_cvt<<<dim3((unsigned)(NW / 1024)), dim3(256), 0, stream>>>(Wo, WoB, (int)NW);
    k_cvt<<<dim3((unsigned)(4 * NW / 1024)), dim3(256), 0, stream>>>(RWq, RWqB, (int)(4 * NW));
    k_cvt<<<dim3((unsigned)(4 * NW / 1024)), dim3(256), 0, stream>>>(RWk, RWkB, (int)(4 * NW));

    dim3 ggrid(NE / BN, BT / BM);
    k_gemm<false><<<ggrid, 256, 0, stream>>>(hsB, WqB, bq, nullptr, Qb, 0.125f);
    k_gemm<false><<<ggrid, 256, 0, stream>>>(hsB, WkB, bk, nullptr, Kb, 1.0f);
    k_gemm<false><<<ggrid, 256, 0, stream>>>(hsB, WvB, bv, nullptr, Vb, 1.0f);
    k_gemm<false><<<ggrid, 256, 0, stream>>>(hsB, RWqB, Rbq, rt, Qrb, 0.125f);
    k_gemm<false><<<ggrid, 256, 0, stream>>>(hsB, RWkB, Rbk, rt, Krb, 1.0f);

    k_vtrans<<<dim3(NB * NH * 16), dim3(256), 0, stream>>>(Vb, Vtb);
    k_attn<<<dim3(NB * NH * 16), dim3(256), 0, stream>>>(Qb, Kb, Qrb, Krb, Vtb, atb);

    k_gemm<true><<<ggrid, 256, 0, stream>>>(atb, WoB, bo, nullptr, d_out, 1.0f);
}

// Round 2
// 553.168 us; speedup vs baseline: 1.0157x; 1.0157x over previous
//
#include <hip/hip_runtime.h>
#include <stdint.h>

#define AS1 __attribute__((address_space(1)))
#define AS3 __attribute__((address_space(3)))

typedef __attribute__((ext_vector_type(8))) short bf16x8;   // 8 bf16 = 4 VGPRs
typedef __attribute__((ext_vector_type(4))) float f32x4;

#define NB 8
#define NT 1024
#define NE 1024
#define NH 16
#define BT (NB * NT)

__device__ __forceinline__ unsigned short f2bf(float f) {
    unsigned int u = __builtin_bit_cast(unsigned int, f);
    u += 0x7FFFu + ((u >> 16) & 1u);          // RNE
    return (unsigned short)(u >> 16);
}
// round-half-up: identical to RNE except exact .5 ties; 2 VALU ops
__device__ __forceinline__ unsigned short f2bfu(float f) {
    unsigned int u = __builtin_bit_cast(unsigned int, f);
    return (unsigned short)((u + 0x8000u) >> 16);
}

// ---------------- f32 -> bf16 conversion (n % 4 == 0) ----------------
__global__ void k_cvt(const float* __restrict__ in, unsigned short* __restrict__ out, int n) {
    int i = (blockIdx.x * 256 + threadIdx.x) * 4;
    if (i >= n) return;
    float4 f = *reinterpret_cast<const float4*>(in + i);
    ushort4 o;
    o.x = f2bf(f.x); o.y = f2bf(f.y); o.z = f2bf(f.z); o.w = f2bf(f.w);
    *reinterpret_cast<ushort4*>(out + i) = o;
}

// ---------------- GEMM: C[m,n] = (sum_k A[m,k]*W[g,n,k] + bias[g,n]) * scale ----
#define BM 128
#define BN 128
#define BK 32

template <bool OUT_F32>
__global__ void k_gemm(const unsigned short* __restrict__ A,
                       const unsigned short* __restrict__ W,
                       const float* __restrict__ bias,
                       const int* __restrict__ rt,
                       void* __restrict__ Cout,
                       float scale)
{
    __shared__ __attribute__((aligned(16))) unsigned short As[BM * BK];
    __shared__ __attribute__((aligned(16))) unsigned short Bs[BN * BK];
    const int tid  = threadIdx.x;
    const int wid  = tid >> 6;
    const int lane = tid & 63;
    const int m0 = blockIdx.y * BM;
    const int n0 = blockIdx.x * BN;
    int g = 0;
    if (rt) g = rt[m0 / NT];
    const unsigned short* Wg = W + (size_t)g * NE * NE;
    const float* biasg = bias + (size_t)g * NE;

    const int wr = (wid >> 1) * 64;
    const int wc = (wid & 1) * 64;
    const int frow = lane & 15;
    const int fk8  = (lane >> 4) * 8;

    f32x4 acc[4][4];
#pragma unroll
    for (int m = 0; m < 4; ++m)
#pragma unroll
        for (int n = 0; n < 4; ++n) acc[m][n] = (f32x4){0.f, 0.f, 0.f, 0.f};

    const int c0 = wid * 2;
    for (int k0 = 0; k0 < NE; k0 += BK) {
#pragma unroll
        for (int i = 0; i < 2; ++i) {
            int ci  = (c0 + i) * 64 + lane;
            int row = ci >> 2;
            int kc  = (ci & 3) * 8;
            const unsigned short* srcA = A  + (size_t)(m0 + row) * NE + k0 + kc;
            const unsigned short* srcB = Wg + (size_t)(n0 + row) * NE + k0 + kc;
            __builtin_amdgcn_global_load_lds((AS1 void*)srcA, (AS3 void*)(As + (c0 + i) * 512), 16, 0, 0);
            __builtin_amdgcn_global_load_lds((AS1 void*)srcB, (AS3 void*)(Bs + (c0 + i) * 512), 16, 0, 0);
        }
        __syncthreads();
        bf16x8 af[4], bfr[4];
#pragma unroll
        for (int m = 0; m < 4; ++m)
            af[m] = *reinterpret_cast<const bf16x8*>(As + (wr + m * 16 + frow) * BK + fk8);
#pragma unroll
        for (int n = 0; n < 4; ++n)
            bfr[n] = *reinterpret_cast<const bf16x8*>(Bs + (wc + n * 16 + frow) * BK + fk8);
#pragma unroll
        for (int m = 0; m < 4; ++m)
#pragma unroll
            for (int n = 0; n < 4; ++n)
                acc[m][n] = __builtin_amdgcn_mfma_f32_16x16x32_bf16(af[m], bfr[n], acc[m][n], 0, 0, 0);
        __syncthreads();
    }

#pragma unroll
    for (int m = 0; m < 4; ++m) {
        int row = m0 + wr + m * 16 + (lane >> 4) * 4;
#pragma unroll
        for (int n = 0; n < 4; ++n) {
            int col = n0 + wc + n * 16 + frow;
            float bv = biasg[col];
            f32x4 v = acc[m][n];
#pragma unroll
            for (int r = 0; r < 4; ++r) {
                float val = (v[r] + bv) * scale;
                if (OUT_F32)
                    ((float*)Cout)[(size_t)(row + r) * NE + col] = val;
                else
                    ((unsigned short*)Cout)[(size_t)(row + r) * NE + col] = f2bf(val);
            }
        }
    }
}

// ---------------- V transpose: Vt[(b,h),d,s] = V[b,s,h*64+d] ----------------
__global__ void k_vtrans(const unsigned short* __restrict__ V, unsigned short* __restrict__ Vt) {
    __shared__ unsigned short tile[64][65];
    const int blk = blockIdx.x;
    const int bh = blk >> 4;
    const int b = bh >> 4;
    const int h = bh & 15;
    const int s0 = (blk & 15) * 64;
    const int tid = threadIdx.x;
#pragma unroll
    for (int i = 0; i < 2; ++i) {
        int seg = tid + i * 256;
        int row = seg >> 3;
        int c8 = (seg & 7) * 8;
        const unsigned short* src = V + (size_t)(b * NT + s0 + row) * NE + h * 64 + c8;
        ushort4 u0 = *reinterpret_cast<const ushort4*>(src);
        ushort4 u1 = *reinterpret_cast<const ushort4*>(src + 4);
        tile[row][c8 + 0] = u0.x; tile[row][c8 + 1] = u0.y;
        tile[row][c8 + 2] = u0.z; tile[row][c8 + 3] = u0.w;
        tile[row][c8 + 4] = u1.x; tile[row][c8 + 5] = u1.y;
        tile[row][c8 + 6] = u1.z; tile[row][c8 + 7] = u1.w;
    }
    __syncthreads();
#pragma unroll
    for (int i = 0; i < 2; ++i) {
        int seg = tid + i * 256;
        int drow = seg >> 3;
        int s8 = (seg & 7) * 8;
        ushort4 u0, u1;
        u0.x = tile[s8 + 0][drow]; u0.y = tile[s8 + 1][drow];
        u0.z = tile[s8 + 2][drow]; u0.w = tile[s8 + 3][drow];
        u1.x = tile[s8 + 4][drow]; u1.y = tile[s8 + 5][drow];
        u1.z = tile[s8 + 6][drow]; u1.w = tile[s8 + 7][drow];
        unsigned short* dst = Vt + (size_t)(bh * 64 + drow) * NT + s0 + s8;
        *reinterpret_cast<ushort4*>(dst) = u0;
        *reinterpret_cast<ushort4*>(dst + 4) = u1;
    }
}

// ---------------- fused dual-stream attention, no-max exp accumulation ------
// Scores are bounded (|s| ~< 3 << 88), so P = exp(s) needs no max-tracking;
// exp(-m) cancels exactly in O/l. Per-lane partial l accumulates in registers;
// one cross-lane reduce at the end. No shfl / no rescale in the K-loop.
__global__ void k_attn(const unsigned short* __restrict__ Q,
                       const unsigned short* __restrict__ K,
                       const unsigned short* __restrict__ Qr,
                       const unsigned short* __restrict__ Kr,
                       const unsigned short* __restrict__ Vt,
                       unsigned short* __restrict__ attnO)
{
    constexpr int PLD = 40;  // 80B rows: 16B-aligned for b128 reads, 4-way max on b16 writes
    __shared__ __attribute__((aligned(16))) unsigned short Pg[4][16 * PLD];
    __shared__ __attribute__((aligned(16))) unsigned short Pr[4][16 * PLD];
    // XCD swizzle: 16 blocks of one (b,h) share 384KB K/Kr/V -> same XCD L2
    const int blk = ((blockIdx.x & 7) << 8) | (blockIdx.x >> 3);
    const int tile16 = blk & 15;
    const int bh = blk >> 4;
    const int b = bh >> 4;
    const int h = bh & 15;
    const int wid = threadIdx.x >> 6;
    const int lane = threadIdx.x & 63;
    const int frow = lane & 15;
    const int g4 = lane >> 4;
    const int fk8 = g4 * 8;
    const int t0 = tile16 * 64 + wid * 16;

    const size_t qoff = (size_t)(b * NT + t0 + frow) * NE + h * 64;
    const bf16x8 qf0 = *reinterpret_cast<const bf16x8*>(Q + qoff + fk8);
    const bf16x8 qf1 = *reinterpret_cast<const bf16x8*>(Q + qoff + 32 + fk8);
    const bf16x8 qr0 = *reinterpret_cast<const bf16x8*>(Qr + qoff + fk8);
    const bf16x8 qr1 = *reinterpret_cast<const bf16x8*>(Qr + qoff + 32 + fk8);

    const unsigned short* Kb  = K  + (size_t)b * NT * NE + h * 64;
    const unsigned short* Krb = Kr + (size_t)b * NT * NE + h * 64;
    const unsigned short* Vtb = Vt + (size_t)bh * 64 * NT;
    unsigned short* Pgw = &Pg[wid][0];
    unsigned short* Prw = &Pr[wid][0];

    f32x4 og[4], orr[4];
    float lgp[4], lrp[4];
#pragma unroll
    for (int i = 0; i < 4; ++i) {
        og[i] = (f32x4){0.f, 0.f, 0.f, 0.f};
        orr[i] = (f32x4){0.f, 0.f, 0.f, 0.f};
        lgp[i] = 0.f; lrp[i] = 0.f;
    }

    for (int s0 = 0; s0 < NT; s0 += 32) {
        const unsigned short* kg0p = Kb  + (size_t)(s0 + frow) * NE + fk8;
        const unsigned short* kg1p = Kb  + (size_t)(s0 + 16 + frow) * NE + fk8;
        const unsigned short* kr0p = Krb + (size_t)(s0 + frow) * NE + fk8;
        const unsigned short* kr1p = Krb + (size_t)(s0 + 16 + frow) * NE + fk8;
        bf16x8 ka0 = *reinterpret_cast<const bf16x8*>(kg0p);
        bf16x8 ka1 = *reinterpret_cast<const bf16x8*>(kg0p + 32);
        bf16x8 kb0 = *reinterpret_cast<const bf16x8*>(kg1p);
        bf16x8 kb1 = *reinterpret_cast<const bf16x8*>(kg1p + 32);
        bf16x8 kc0 = *reinterpret_cast<const bf16x8*>(kr0p);
        bf16x8 kc1 = *reinterpret_cast<const bf16x8*>(kr0p + 32);
        bf16x8 kd0 = *reinterpret_cast<const bf16x8*>(kr1p);
        bf16x8 kd1 = *reinterpret_cast<const bf16x8*>(kr1p + 32);
        bf16x8 vb0 = *reinterpret_cast<const bf16x8*>(Vtb + (size_t)(frow)      * NT + s0 + fk8);
        bf16x8 vb1 = *reinterpret_cast<const bf16x8*>(Vtb + (size_t)(16 + frow) * NT + s0 + fk8);
        bf16x8 vb2 = *reinterpret_cast<const bf16x8*>(Vtb + (size_t)(32 + frow) * NT + s0 + fk8);
        bf16x8 vb3 = *reinterpret_cast<const bf16x8*>(Vtb + (size_t)(48 + frow) * NT + s0 + fk8);

        const f32x4 z = (f32x4){0.f, 0.f, 0.f, 0.f};
        f32x4 sg0 = __builtin_amdgcn_mfma_f32_16x16x32_bf16(qf0, ka0, z, 0, 0, 0);
        f32x4 sg1 = __builtin_amdgcn_mfma_f32_16x16x32_bf16(qf0, kb0, z, 0, 0, 0);
        f32x4 sr0 = __builtin_amdgcn_mfma_f32_16x16x32_bf16(qr0, kc0, z, 0, 0, 0);
        f32x4 sr1 = __builtin_amdgcn_mfma_f32_16x16x32_bf16(qr0, kd0, z, 0, 0, 0);
        sg0 = __builtin_amdgcn_mfma_f32_16x16x32_bf16(qf1, ka1, sg0, 0, 0, 0);
        sg1 = __builtin_amdgcn_mfma_f32_16x16x32_bf16(qf1, kb1, sg1, 0, 0, 0);
        sr0 = __builtin_amdgcn_mfma_f32_16x16x32_bf16(qr1, kc1, sr0, 0, 0, 0);
        sr1 = __builtin_amdgcn_mfma_f32_16x16x32_bf16(qr1, kd1, sr1, 0, 0, 0);

#pragma unroll
        for (int r = 0; r < 4; ++r) {
            float pg0 = __expf(sg0[r]);
            float pg1 = __expf(sg1[r]);
            float pr0 = __expf(sr0[r]);
            float pr1 = __expf(sr1[r]);
            lgp[r] += pg0 + pg1;
            lrp[r] += pr0 + pr1;
            const int row = (g4 * 4 + r) * PLD;
            Pgw[row + frow]      = f2bfu(pg0);
            Pgw[row + 16 + frow] = f2bfu(pg1);
            Prw[row + frow]      = f2bfu(pr0);
            Prw[row + 16 + frow] = f2bfu(pr1);
        }
        asm volatile("s_waitcnt lgkmcnt(0)" ::: "memory");  // P visible to same-wave lanes
        bf16x8 pag = *reinterpret_cast<const bf16x8*>(Pgw + frow * PLD + fk8);
        bf16x8 par = *reinterpret_cast<const bf16x8*>(Prw + frow * PLD + fk8);
        og[0]  = __builtin_amdgcn_mfma_f32_16x16x32_bf16(pag, vb0, og[0], 0, 0, 0);
        orr[0] = __builtin_amdgcn_mfma_f32_16x16x32_bf16(par, vb0, orr[0], 0, 0, 0);
        og[1]  = __builtin_amdgcn_mfma_f32_16x16x32_bf16(pag, vb1, og[1], 0, 0, 0);
        orr[1] = __builtin_amdgcn_mfma_f32_16x16x32_bf16(par, vb1, orr[1], 0, 0, 0);
        og[2]  = __builtin_amdgcn_mfma_f32_16x16x32_bf16(pag, vb2, og[2], 0, 0, 0);
        orr[2] = __builtin_amdgcn_mfma_f32_16x16x32_bf16(par, vb2, orr[2], 0, 0, 0);
        og[3]  = __builtin_amdgcn_mfma_f32_16x16x32_bf16(pag, vb3, og[3], 0, 0, 0);
        orr[3] = __builtin_amdgcn_mfma_f32_16x16x32_bf16(par, vb3, orr[3], 0, 0, 0);
    }

    // one-time cross-lane reduce of the row sums (over the 16 frow lanes)
#pragma unroll
    for (int off = 1; off <= 8; off <<= 1) {
#pragma unroll
        for (int r = 0; r < 4; ++r) {
            lgp[r] += __shfl_xor(lgp[r], off);
            lrp[r] += __shfl_xor(lrp[r], off);
        }
    }
    float ig[4], ir[4];
#pragma unroll
    for (int r = 0; r < 4; ++r) { ig[r] = 0.45f / lgp[r]; ir[r] = 0.05f / lrp[r]; }
#pragma unroll
    for (int nf2 = 0; nf2 < 4; ++nf2) {
#pragma unroll
        for (int r = 0; r < 4; ++r) {
            float val = og[nf2][r] * ig[r] + orr[nf2][r] * ir[r];
            int t = t0 + g4 * 4 + r;
            attnO[(size_t)(b * NT + t) * NE + h * 64 + nf2 * 16 + frow] = f2bf(val);
        }
    }
}

// ---------------- launcher ----------------
extern "C" void kernel_launch(void* const* d_in, const int* in_sizes, int n_in,
                              void* d_out, int out_size, void* d_ws, size_t ws_size,
                              hipStream_t stream)
{
    const float* hs  = (const float*)d_in[0];
    const int*   rt  = (const int*)d_in[1];
    const float* Wq  = (const float*)d_in[2];
    const float* bq  = (const float*)d_in[3];
    const float* Wk  = (const float*)d_in[4];
    const float* bk  = (const float*)d_in[5];
    const float* Wv  = (const float*)d_in[6];
    const float* bv  = (const float*)d_in[7];
    const float* Wo  = (const float*)d_in[8];
    const float* bo  = (const float*)d_in[9];
    const float* RWq = (const float*)d_in[10];
    const float* Rbq = (const float*)d_in[11];
    const float* RWk = (const float*)d_in[12];
    const float* Rbk = (const float*)d_in[13];

    unsigned short* w = (unsigned short*)d_ws;
    const size_t NBT = (size_t)BT * NE;   // 8M elems
    const size_t NW  = (size_t)NE * NE;   // 1M elems
    unsigned short* hsB  = w; w += NBT;
    unsigned short* Qb   = w; w += NBT;
    unsigned short* Kb   = w; w += NBT;
    unsigned short* Vb   = w; w += NBT;
    unsigned short* Qrb  = w; w += NBT;
    unsigned short* Krb  = w; w += NBT;
    unsigned short* Vtb  = w; w += NBT;
    unsigned short* atb  = w; w += NBT;
    unsigned short* WqB  = w; w += NW;
    unsigned short* WkB  = w; w += NW;
    unsigned short* WvB  = w; w += NW;
    unsigned short* WoB  = w; w += NW;
    unsigned short* RWqB = w; w += 4 * NW;
    unsigned short* RWkB = w; w += 4 * NW;

    k_cvt<<<dim3((unsigned)(NBT / 1024)), dim3(256), 0, stream>>>(hs, hsB, (int)NBT);
    k_cvt<<<dim3((unsigned)(NW / 1024)), dim3(256), 0, stream>>>(Wq, WqB, (int)NW);
    k_cvt<<<dim3((unsigned)(NW / 1024)), dim3(256), 0, stream>>>(Wk, WkB, (int)NW);
    k_cvt<<<dim3((unsigned)(NW / 1024)), dim3(256), 0, stream>>>(Wv, WvB, (int)NW);
    k_cvt<<<dim3((unsigned)(NW / 1024)), dim3(256), 0, stream>>>(Wo, WoB, (int)NW);
    k_cvt<<<dim3((unsigned)(4 * NW / 1024)), dim3(256), 0, stream>>>(RWq, RWqB, (int)(4 * NW));
    k_cvt<<<dim3((unsigned)(4 * NW / 1024)), dim3(256), 0, stream>>>(RWk, RWkB, (int)(4 * NW));

    dim3 ggrid(NE / BN, BT / BM);
    k_gemm<false><<<ggrid, 256, 0, stream>>>(hsB, WqB, bq, nullptr, Qb, 0.125f);
    k_gemm<false><<<ggrid, 256, 0, stream>>>(hsB, WkB, bk, nullptr, Kb, 1.0f);
    k_gemm<false><<<ggrid, 256, 0, stream>>>(hsB, WvB, bv, nullptr, Vb, 1.0f);
    k_gemm<false><<<ggrid, 256, 0, stream>>>(hsB, RWqB, Rbq, rt, Qrb, 0.125f);
    k_gemm<false><<<ggrid, 256, 0, stream>>>(hsB, RWkB, Rbk, rt, Krb, 1.0f);

    k_vtrans<<<dim3(NB * NH * 16), dim3(256), 0, stream>>>(Vb, Vtb);
    k_attn<<<dim3(NB * NH * 16), dim3(256), 0, stream>>>(Qb, Kb, Qrb, Krb, Vtb, atb);

    k_gemm<true><<<ggrid, 256, 0, stream>>>(atb, WoB, bo, nullptr, d_out, 1.0f);
}

// Round 3
// 322.045 us; speedup vs baseline: 1.7446x; 1.7177x over previous
//
#include <hip/hip_runtime.h>
#include <stdint.h>

#define AS1 __attribute__((address_space(1)))
#define AS3 __attribute__((address_space(3)))

typedef __attribute__((ext_vector_type(8))) short bf16x8;   // 8 bf16 = 4 VGPRs
typedef __attribute__((ext_vector_type(4))) float f32x4;

#define NB 8
#define NT 1024
#define NE 1024
#define NH 16
#define BT (NB * NT)

__device__ __forceinline__ unsigned short f2bf(float f) {
    unsigned int u = __builtin_bit_cast(unsigned int, f);
    u += 0x7FFFu + ((u >> 16) & 1u);          // RNE
    return (unsigned short)(u >> 16);
}
// round-half-up: identical to RNE except exact .5 ties; 2 VALU ops
__device__ __forceinline__ unsigned short f2bfu(float f) {
    unsigned int u = __builtin_bit_cast(unsigned int, f);
    return (unsigned short)((u + 0x8000u) >> 16);
}

// ---------------- f32 -> bf16 conversion (n % 4 == 0) ----------------
__global__ void k_cvt(const float* __restrict__ in, unsigned short* __restrict__ out, int n) {
    int i = (blockIdx.x * 256 + threadIdx.x) * 4;
    if (i >= n) return;
    float4 f = *reinterpret_cast<const float4*>(in + i);
    ushort4 o;
    o.x = f2bf(f.x); o.y = f2bf(f.y); o.z = f2bf(f.z); o.w = f2bf(f.w);
    *reinterpret_cast<ushort4*>(out + i) = o;
}

// ---------------- GEMM: C[m,n] = (sum_k A[m,k]*W[g,n,k] + bias[g,n]) * scale ----
#define BM 128
#define BN 128
#define BK 32

template <bool OUT_F32>
__global__ void k_gemm(const unsigned short* __restrict__ A,
                       const unsigned short* __restrict__ W,
                       const float* __restrict__ bias,
                       const int* __restrict__ rt,
                       void* __restrict__ Cout,
                       float scale)
{
    __shared__ __attribute__((aligned(16))) unsigned short As[BM * BK];
    __shared__ __attribute__((aligned(16))) unsigned short Bs[BN * BK];
    const int tid  = threadIdx.x;
    const int wid  = tid >> 6;
    const int lane = tid & 63;
    const int m0 = blockIdx.y * BM;
    const int n0 = blockIdx.x * BN;
    int g = 0;
    if (rt) g = rt[m0 / NT];
    const unsigned short* Wg = W + (size_t)g * NE * NE;
    const float* biasg = bias + (size_t)g * NE;

    const int wr = (wid >> 1) * 64;
    const int wc = (wid & 1) * 64;
    const int frow = lane & 15;
    const int fk8  = (lane >> 4) * 8;

    f32x4 acc[4][4];
#pragma unroll
    for (int m = 0; m < 4; ++m)
#pragma unroll
        for (int n = 0; n < 4; ++n) acc[m][n] = (f32x4){0.f, 0.f, 0.f, 0.f};

    const int c0 = wid * 2;
    for (int k0 = 0; k0 < NE; k0 += BK) {
#pragma unroll
        for (int i = 0; i < 2; ++i) {
            int ci  = (c0 + i) * 64 + lane;
            int row = ci >> 2;
            int kc  = (ci & 3) * 8;
            const unsigned short* srcA = A  + (size_t)(m0 + row) * NE + k0 + kc;
            const unsigned short* srcB = Wg + (size_t)(n0 + row) * NE + k0 + kc;
            __builtin_amdgcn_global_load_lds((AS1 void*)srcA, (AS3 void*)(As + (c0 + i) * 512), 16, 0, 0);
            __builtin_amdgcn_global_load_lds((AS1 void*)srcB, (AS3 void*)(Bs + (c0 + i) * 512), 16, 0, 0);
        }
        __syncthreads();
        bf16x8 af[4], bfr[4];
#pragma unroll
        for (int m = 0; m < 4; ++m)
            af[m] = *reinterpret_cast<const bf16x8*>(As + (wr + m * 16 + frow) * BK + fk8);
#pragma unroll
        for (int n = 0; n < 4; ++n)
            bfr[n] = *reinterpret_cast<const bf16x8*>(Bs + (wc + n * 16 + frow) * BK + fk8);
#pragma unroll
        for (int m = 0; m < 4; ++m)
#pragma unroll
            for (int n = 0; n < 4; ++n)
                acc[m][n] = __builtin_amdgcn_mfma_f32_16x16x32_bf16(af[m], bfr[n], acc[m][n], 0, 0, 0);
        __syncthreads();
    }

#pragma unroll
    for (int m = 0; m < 4; ++m) {
        int row = m0 + wr + m * 16 + (lane >> 4) * 4;
#pragma unroll
        for (int n = 0; n < 4; ++n) {
            int col = n0 + wc + n * 16 + frow;
            float bv = biasg[col];
            f32x4 v = acc[m][n];
#pragma unroll
            for (int r = 0; r < 4; ++r) {
                float val = (v[r] + bv) * scale;
                if (OUT_F32)
                    ((float*)Cout)[(size_t)(row + r) * NE + col] = val;
                else
                    ((unsigned short*)Cout)[(size_t)(row + r) * NE + col] = f2bf(val);
            }
        }
    }
}

// ---------------- V transpose: Vt[(b,h),d,s] = V[b,s,h*64+d] ----------------
__global__ void k_vtrans(const unsigned short* __restrict__ V, unsigned short* __restrict__ Vt) {
    __shared__ unsigned short tile[64][65];
    const int blk = blockIdx.x;
    const int bh = blk >> 4;
    const int b = bh >> 4;
    const int h = bh & 15;
    const int s0 = (blk & 15) * 64;
    const int tid = threadIdx.x;
#pragma unroll
    for (int i = 0; i < 2; ++i) {
        int seg = tid + i * 256;
        int row = seg >> 3;
        int c8 = (seg & 7) * 8;
        const unsigned short* src = V + (size_t)(b * NT + s0 + row) * NE + h * 64 + c8;
        ushort4 u0 = *reinterpret_cast<const ushort4*>(src);
        ushort4 u1 = *reinterpret_cast<const ushort4*>(src + 4);
        tile[row][c8 + 0] = u0.x; tile[row][c8 + 1] = u0.y;
        tile[row][c8 + 2] = u0.z; tile[row][c8 + 3] = u0.w;
        tile[row][c8 + 4] = u1.x; tile[row][c8 + 5] = u1.y;
        tile[row][c8 + 6] = u1.z; tile[row][c8 + 7] = u1.w;
    }
    __syncthreads();
#pragma unroll
    for (int i = 0; i < 2; ++i) {
        int seg = tid + i * 256;
        int drow = seg >> 3;
        int s8 = (seg & 7) * 8;
        ushort4 u0, u1;
        u0.x = tile[s8 + 0][drow]; u0.y = tile[s8 + 1][drow];
        u0.z = tile[s8 + 2][drow]; u0.w = tile[s8 + 3][drow];
        u1.x = tile[s8 + 4][drow]; u1.y = tile[s8 + 5][drow];
        u1.z = tile[s8 + 6][drow]; u1.w = tile[s8 + 7][drow];
        unsigned short* dst = Vt + (size_t)(bh * 64 + drow) * NT + s0 + s8;
        *reinterpret_cast<ushort4*>(dst) = u0;
        *reinterpret_cast<ushort4*>(dst + 4) = u1;
    }
}

// ---------------- fused dual-stream attention, LDS-staged K/Kr/V ------------
// 8 waves x 16 q-rows = 128 q-rows per block; KVBLK=32; double-buffered LDS
// staging via global_load_lds; XOR-swizzled tile layout so ds_read_b128 frag
// reads are bank-conflict-free (stage source and read use the same involution).
// No-max exp accumulation (scores bounded; exp(-m) cancels in O/l).
__global__ void k_attn(const unsigned short* __restrict__ Q,
                       const unsigned short* __restrict__ K,
                       const unsigned short* __restrict__ Qr,
                       const unsigned short* __restrict__ Kr,
                       const unsigned short* __restrict__ Vt,
                       unsigned short* __restrict__ attnO)
{
    constexpr int PLD = 40;
    __shared__ __attribute__((aligned(16))) unsigned short KV[2][6144];   // Kg|Kr|V, 12KB each
    __shared__ __attribute__((aligned(16))) unsigned short Pg[8][16 * PLD];
    __shared__ __attribute__((aligned(16))) unsigned short Pr[8][16 * PLD];

    // bijective XCD swizzle: 1024 blocks, 128/XCD -> 16 heads/XCD, all 8
    // blocks of one head on the same XCD (K/Kr/V stay in that XCD's L2)
    const int blk = (blockIdx.x & 7) * 128 + (blockIdx.x >> 3);
    const int tile = blk & 7;
    const int bh = blk >> 3;
    const int b = bh >> 4;
    const int h = bh & 15;
    const int wid = threadIdx.x >> 6;
    const int lane = threadIdx.x & 63;
    const int frow = lane & 15;
    const int g4 = lane >> 4;
    const int fk8 = g4 * 8;
    const int t0 = tile * 128 + wid * 16;

    const size_t qoff = (size_t)(b * NT + t0 + frow) * NE + h * 64;
    const bf16x8 qf0 = *reinterpret_cast<const bf16x8*>(Q + qoff + fk8);
    const bf16x8 qf1 = *reinterpret_cast<const bf16x8*>(Q + qoff + 32 + fk8);
    const bf16x8 qr0 = *reinterpret_cast<const bf16x8*>(Qr + qoff + fk8);
    const bf16x8 qr1 = *reinterpret_cast<const bf16x8*>(Qr + qoff + 32 + fk8);

    const unsigned short* Kb  = K  + (size_t)b * NT * NE + h * 64;
    const unsigned short* Krb = Kr + (size_t)b * NT * NE + h * 64;
    const unsigned short* Vtb = Vt + (size_t)bh * 64 * NT;
    unsigned short* Pgw = &Pg[wid][0];
    unsigned short* Prw = &Pr[wid][0];

    f32x4 og[4], orr[4];
    float lgp[4], lrp[4];
#pragma unroll
    for (int i = 0; i < 4; ++i) {
        og[i] = (f32x4){0.f, 0.f, 0.f, 0.f};
        orr[i] = (f32x4){0.f, 0.f, 0.f, 0.f};
        lgp[i] = 0.f; lrp[i] = 0.f;
    }

    // stage one 12KB buffer: cg 0-3 Kg[32 s][64 k], 4-7 Kr, 8-11 V[64 d][32 s]
    // K layout: lds chunk (row, cb) holds K[s0+row][8*(cb ^ (row&7)) ..+8]
    // V layout: lds chunk (d, cb)   holds V[d-row][s0 + 8*(cb ^ (d&3)) ..+8]
    auto stage = [&](int buf, int s0) {
#pragma unroll
        for (int i = 0; i < 2; ++i) {
            int cg = (i == 0) ? wid : (8 + wid);
            if (i == 1 && wid >= 4) break;
            int c = cg * 64 + lane;
            const unsigned short* src;
            if (cg < 8) {
                const unsigned short* base = (cg < 4) ? Kb : Krb;
                int cc = c & 255;
                int row = cc >> 3, cb = cc & 7;
                src = base + (size_t)(s0 + row) * NE + ((cb ^ (row & 7)) * 8);
            } else {
                int cc = c - 512;
                int d = cc >> 2, cb = cc & 3;
                src = Vtb + (size_t)d * NT + s0 + ((cb ^ (d & 3)) * 8);
            }
            __builtin_amdgcn_global_load_lds((AS1 void*)src, (AS3 void*)(&KV[buf][cg * 512]), 16, 0, 0);
        }
    };

    stage(0, 0);
    __syncthreads();
    int cur = 0;
    for (int t = 0; t < NT / 32; ++t) {
        if (t + 1 < NT / 32) stage(cur ^ 1, (t + 1) * 32);

        const unsigned short* Kl  = &KV[cur][0];
        const unsigned short* Krl = &KV[cur][2048];
        const unsigned short* Vl  = &KV[cur][4096];
        bf16x8 kg[2][2], kr[2][2], vb[4];
#pragma unroll
        for (int nf = 0; nf < 2; ++nf)
#pragma unroll
            for (int kh = 0; kh < 2; ++kh) {
                int idx = (nf * 16 + frow) * 64 + (((g4 + 4 * kh) ^ (frow & 7)) * 8);
                kg[nf][kh] = *reinterpret_cast<const bf16x8*>(Kl + idx);
                kr[nf][kh] = *reinterpret_cast<const bf16x8*>(Krl + idx);
            }
#pragma unroll
        for (int nf2 = 0; nf2 < 4; ++nf2)
            vb[nf2] = *reinterpret_cast<const bf16x8*>(Vl + (nf2 * 16 + frow) * 32 + ((g4 ^ (frow & 3)) * 8));

        const f32x4 z = (f32x4){0.f, 0.f, 0.f, 0.f};
        f32x4 sg0 = __builtin_amdgcn_mfma_f32_16x16x32_bf16(qf0, kg[0][0], z, 0, 0, 0);
        f32x4 sg1 = __builtin_amdgcn_mfma_f32_16x16x32_bf16(qf0, kg[1][0], z, 0, 0, 0);
        f32x4 sr0 = __builtin_amdgcn_mfma_f32_16x16x32_bf16(qr0, kr[0][0], z, 0, 0, 0);
        f32x4 sr1 = __builtin_amdgcn_mfma_f32_16x16x32_bf16(qr0, kr[1][0], z, 0, 0, 0);
        sg0 = __builtin_amdgcn_mfma_f32_16x16x32_bf16(qf1, kg[0][1], sg0, 0, 0, 0);
        sg1 = __builtin_amdgcn_mfma_f32_16x16x32_bf16(qf1, kg[1][1], sg1, 0, 0, 0);
        sr0 = __builtin_amdgcn_mfma_f32_16x16x32_bf16(qr1, kr[0][1], sr0, 0, 0, 0);
        sr1 = __builtin_amdgcn_mfma_f32_16x16x32_bf16(qr1, kr[1][1], sr1, 0, 0, 0);

#pragma unroll
        for (int r = 0; r < 4; ++r) {
            float pg0 = __expf(sg0[r]);
            float pg1 = __expf(sg1[r]);
            float pr0 = __expf(sr0[r]);
            float pr1 = __expf(sr1[r]);
            lgp[r] += pg0 + pg1;
            lrp[r] += pr0 + pr1;
            const int row = (g4 * 4 + r) * PLD;
            Pgw[row + frow]      = f2bfu(pg0);
            Pgw[row + 16 + frow] = f2bfu(pg1);
            Prw[row + frow]      = f2bfu(pr0);
            Prw[row + 16 + frow] = f2bfu(pr1);
        }
        asm volatile("s_waitcnt lgkmcnt(0)" ::: "memory");  // P visible to same-wave lanes
        bf16x8 pag = *reinterpret_cast<const bf16x8*>(Pgw + frow * PLD + fk8);
        bf16x8 par = *reinterpret_cast<const bf16x8*>(Prw + frow * PLD + fk8);
        og[0]  = __builtin_amdgcn_mfma_f32_16x16x32_bf16(pag, vb[0], og[0], 0, 0, 0);
        orr[0] = __builtin_amdgcn_mfma_f32_16x16x32_bf16(par, vb[0], orr[0], 0, 0, 0);
        og[1]  = __builtin_amdgcn_mfma_f32_16x16x32_bf16(pag, vb[1], og[1], 0, 0, 0);
        orr[1] = __builtin_amdgcn_mfma_f32_16x16x32_bf16(par, vb[1], orr[1], 0, 0, 0);
        og[2]  = __builtin_amdgcn_mfma_f32_16x16x32_bf16(pag, vb[2], og[2], 0, 0, 0);
        orr[2] = __builtin_amdgcn_mfma_f32_16x16x32_bf16(par, vb[2], orr[2], 0, 0, 0);
        og[3]  = __builtin_amdgcn_mfma_f32_16x16x32_bf16(pag, vb[3], og[3], 0, 0, 0);
        orr[3] = __builtin_amdgcn_mfma_f32_16x16x32_bf16(par, vb[3], orr[3], 0, 0, 0);

        __syncthreads();   // drains vmcnt (next buffer staged) + read/overwrite fence
        cur ^= 1;
    }

    // one-time cross-lane reduce of row sums (over the 16 frow lanes)
#pragma unroll
    for (int off = 1; off <= 8; off <<= 1) {
#pragma unroll
        for (int r = 0; r < 4; ++r) {
            lgp[r] += __shfl_xor(lgp[r], off);
            lrp[r] += __shfl_xor(lrp[r], off);
        }
    }
    float ig[4], ir[4];
#pragma unroll
    for (int r = 0; r < 4; ++r) { ig[r] = 0.45f / lgp[r]; ir[r] = 0.05f / lrp[r]; }
#pragma unroll
    for (int nf2 = 0; nf2 < 4; ++nf2) {
#pragma unroll
        for (int r = 0; r < 4; ++r) {
            float val = og[nf2][r] * ig[r] + orr[nf2][r] * ir[r];
            int t = t0 + g4 * 4 + r;
            attnO[(size_t)(b * NT + t) * NE + h * 64 + nf2 * 16 + frow] = f2bf(val);
        }
    }
}

// ---------------- launcher ----------------
extern "C" void kernel_launch(void* const* d_in, const int* in_sizes, int n_in,
                              void* d_out, int out_size, void* d_ws, size_t ws_size,
                              hipStream_t stream)
{
    const float* hs  = (const float*)d_in[0];
    const int*   rt  = (const int*)d_in[1];
    const float* Wq  = (const float*)d_in[2];
    const float* bq  = (const float*)d_in[3];
    const float* Wk  = (const float*)d_in[4];
    const float* bk  = (const float*)d_in[5];
    const float* Wv  = (const float*)d_in[6];
    const float* bv  = (const float*)d_in[7];
    const float* Wo  = (const float*)d_in[8];
    const float* bo  = (const float*)d_in[9];
    const float* RWq = (const float*)d_in[10];
    const float* Rbq = (const float*)d_in[11];
    const float* RWk = (const float*)d_in[12];
    const float* Rbk = (const float*)d_in[13];

    unsigned short* w = (unsigned short*)d_ws;
    const size_t NBT = (size_t)BT * NE;   // 8M elems
    const size_t NW  = (size_t)NE * NE;   // 1M elems
    unsigned short* hsB  = w; w += NBT;
    unsigned short* Qb   = w; w += NBT;
    unsigned short* Kb   = w; w += NBT;
    unsigned short* Vb   = w; w += NBT;
    unsigned short* Qrb  = w; w += NBT;
    unsigned short* Krb  = w; w += NBT;
    unsigned short* Vtb  = w; w += NBT;
    unsigned short* atb  = w; w += NBT;
    unsigned short* WqB  = w; w += NW;
    unsigned short* WkB  = w; w += NW;
    unsigned short* WvB  = w; w += NW;
    unsigned short* WoB  = w; w += NW;
    unsigned short* RWqB = w; w += 4 * NW;
    unsigned short* RWkB = w; w += 4 * NW;

    k_cvt<<<dim3((unsigned)(NBT / 1024)), dim3(256), 0, stream>>>(hs, hsB, (int)NBT);
    k_cvt<<<dim3((unsigned)(NW / 1024)), dim3(256), 0, stream>>>(Wq, WqB, (int)NW);
    k_cvt<<<dim3((unsigned)(NW / 1024)), dim3(256), 0, stream>>>(Wk, WkB, (int)NW);
    k_cvt<<<dim3((unsigned)(NW / 1024)), dim3(256), 0, stream>>>(Wv, WvB, (int)NW);
    k_cvt<<<dim3((unsigned)(NW / 1024)), dim3(256), 0, stream>>>(Wo, WoB, (int)NW);
    k_cvt<<<dim3((unsigned)(4 * NW / 1024)), dim3(256), 0, stream>>>(RWq, RWqB, (int)(4 * NW));
    k_cvt<<<dim3((unsigned)(4 * NW / 1024)), dim3(256), 0, stream>>>(RWk, RWkB, (int)(4 * NW));

    dim3 ggrid(NE / BN, BT / BM);
    k_gemm<false><<<ggrid, 256, 0, stream>>>(hsB, WqB, bq, nullptr, Qb, 0.125f);
    k_gemm<false><<<ggrid, 256, 0, stream>>>(hsB, WkB, bk, nullptr, Kb, 1.0f);
    k_gemm<false><<<ggrid, 256, 0, stream>>>(hsB, WvB, bv, nullptr, Vb, 1.0f);
    k_gemm<false><<<ggrid, 256, 0, stream>>>(hsB, RWqB, Rbq, rt, Qrb, 0.125f);
    k_gemm<false><<<ggrid, 256, 0, stream>>>(hsB, RWkB, Rbk, rt, Krb, 1.0f);

    k_vtrans<<<dim3(NB * NH * 16), dim3(256), 0, stream>>>(Vb, Vtb);
    k_attn<<<dim3(NB * NH * 8), dim3(512), 0, stream>>>(Qb, Kb, Qrb, Krb, Vtb, atb);

    k_gemm<true><<<ggrid, 256, 0, stream>>>(atb, WoB, bo, nullptr, d_out, 1.0f);
}

// Round 4
// 274.697 us; speedup vs baseline: 2.0453x; 1.1724x over previous
//
#include <hip/hip_runtime.h>
#include <stdint.h>

#define AS1 __attribute__((address_space(1)))
#define AS3 __attribute__((address_space(3)))

typedef __attribute__((ext_vector_type(8))) short bf16x8;   // 8 bf16 = 4 VGPRs
typedef __attribute__((ext_vector_type(4))) float f32x4;

#define NB 8
#define NT 1024
#define NE 1024
#define NH 16
#define BT (NB * NT)

__device__ __forceinline__ unsigned short f2bf(float f) {
    unsigned int u = __builtin_bit_cast(unsigned int, f);
    u += 0x7FFFu + ((u >> 16) & 1u);          // RNE
    return (unsigned short)(u >> 16);
}
// round-half-up: identical to RNE except exact .5 ties; 2 VALU ops
__device__ __forceinline__ unsigned short f2bfu(float f) {
    unsigned int u = __builtin_bit_cast(unsigned int, f);
    return (unsigned short)((u + 0x8000u) >> 16);
}

// ---------------- f32 -> bf16 conversion (n % 4 == 0) ----------------
__global__ void k_cvt(const float* __restrict__ in, unsigned short* __restrict__ out, int n) {
    int i = (blockIdx.x * 256 + threadIdx.x) * 4;
    if (i >= n) return;
    float4 f = *reinterpret_cast<const float4*>(in + i);
    ushort4 o;
    o.x = f2bf(f.x); o.y = f2bf(f.y); o.z = f2bf(f.z); o.w = f2bf(f.w);
    *reinterpret_cast<ushort4*>(out + i) = o;
}

// ============ 256x256 8-phase GEMM (T2+T3+T4+T5), C = A·W^T + bias =========
// A: [8192 x 1024] bf16 row-major. W: [(G)x1024x1024] bf16 (K contiguous).
// 8 waves (2m x 4n), per-wave 128x64 out, BK=64, 2 K-tiles per 8-phase iter,
// 128KB LDS double-buffer, counted vmcnt(2), chunk-XOR swizzle both sides.
struct GJob {
    const unsigned short* W;
    const float* bias;
    void* out;
    float scale;
    int routed;
};

template <bool OUT_F32>
__global__ __launch_bounds__(512, 2)
void k_gemm256(const unsigned short* __restrict__ A,
               GJob j0, GJob j1, GJob j2, GJob j3, GJob j4,
               const int* __restrict__ rt, int cpx)
{
    __shared__ __attribute__((aligned(16))) unsigned short LB[2][2][2][128 * 64];
    // [dbuf][mat 0=A 1=B][half][128 rows x 64 k], chunk-XOR swizzled

    const int flat = blockIdx.x;
    const int wgid = (flat & 7) * cpx + (flat >> 3);   // XCD-chunked, nwg%8==0
    const int pz  = wgid >> 7;
    const int rem = wgid & 127;
    const int by = rem >> 2, bx = rem & 3;
    const int m0 = by << 8, n0 = bx << 8;

    GJob jb = j0;
    if (pz == 1) jb = j1;
    else if (pz == 2) jb = j2;
    else if (pz == 3) jb = j3;
    else if (pz == 4) jb = j4;
    int g = jb.routed ? rt[m0 >> 10] : 0;
    const unsigned short* Wg = jb.W + (size_t)g * NE * NE;

    const int tid  = threadIdx.x;
    const int wid  = tid >> 6;
    const int lane = tid & 63;
    const int frow = lane & 15;
    const int g4   = lane >> 4;
    const int wm = wid >> 2, wn = wid & 3;

    // staging geometry: half-tile = 128 rows x 8 chunks(16B) = 1024 chunks;
    // thread stages chunks c = tid + j*512. LDS linear dest; source chunk
    // pre-swizzled: p ^ (row&7)  (involution; read side applies the same XOR)
    const int rh0  = tid >> 3;                       // row of chunk j=0
    const int swz8 = ((tid & 7) ^ (rh0 & 7)) * 8;    // swizzled k-chunk (elems)
    const unsigned short* baseA = A  + (size_t)m0 * NE;
    const unsigned short* baseB = Wg + (size_t)n0 * NE;

    auto STAGE = [&](int d, int mat, int half, int kt) {
        const unsigned short* base = mat ? baseB : baseA;
#pragma unroll
        for (int j = 0; j < 2; ++j) {
            const unsigned short* src =
                base + (size_t)(half * 128 + rh0 + j * 64) * NE + kt * 64 + swz8;
            __builtin_amdgcn_global_load_lds((AS1 void*)src,
                (AS3 void*)&LB[d][mat][half][(wid * 64 + j * 512) * 8], 16, 0, 0);
        }
    };

    f32x4 acc[8][4];
#pragma unroll
    for (int m = 0; m < 8; ++m)
#pragma unroll
        for (int n = 0; n < 4; ++n) acc[m][n] = (f32x4){0.f, 0.f, 0.f, 0.f};

    bf16x8 a4[4], b4[4];
    auto RDA = [&](int d, int mh, int kh) {
#pragma unroll
        for (int mf = 0; mf < 4; ++mf) {
            int rh = mh * 64 + mf * 16 + frow;
            int off = rh * 64 + (((kh * 4 + g4) ^ (frow & 7)) * 8);
            a4[mf] = *reinterpret_cast<const bf16x8*>(&LB[d][0][wm][off]);
        }
    };
    auto RDB = [&](int d, int kh) {
#pragma unroll
        for (int nf = 0; nf < 4; ++nf) {
            int rh = (wn & 1) * 64 + nf * 16 + frow;
            int off = rh * 64 + (((kh * 4 + g4) ^ (frow & 7)) * 8);
            b4[nf] = *reinterpret_cast<const bf16x8*>(&LB[d][1][wn >> 1][off]);
        }
    };
    auto MM = [&](int mh) {
        __builtin_amdgcn_s_setprio(1);
#pragma unroll
        for (int mf = 0; mf < 4; ++mf)
#pragma unroll
            for (int nf = 0; nf < 4; ++nf)
                acc[mh * 4 + mf][nf] =
                    __builtin_amdgcn_mfma_f32_16x16x32_bf16(a4[mf], b4[nf], acc[mh * 4 + mf][nf], 0, 0, 0);
        __builtin_amdgcn_s_setprio(0);
    };

#define BARX __builtin_amdgcn_s_barrier()
#define LGK0 asm volatile("s_waitcnt lgkmcnt(0)" ::: "memory")
#define VMC2 asm volatile("s_waitcnt vmcnt(2)" ::: "memory")

    // prologue: K-tile 0 (dbuf0, 4 half-tiles) + Bh0 of K-tile 1 (dbuf1)
    STAGE(0, 0, 0, 0); STAGE(0, 0, 1, 0); STAGE(0, 1, 0, 0); STAGE(0, 1, 1, 0);
    STAGE(1, 1, 0, 1);
    VMC2; BARX;

#pragma unroll 1
    for (int i = 0; i < 8; ++i) {
        const int t = 2 * i;
        const bool pre = (i < 7);
        // ph0: read A(t) mh0 k0 + B(t) k0 | stage Bh1(t+1)
        RDA(0, 0, 0); RDB(0, 0); STAGE(1, 1, 1, t + 1);
        BARX; LGK0; MM(0); BARX;
        // ph1: read A(t) mh1 k0 | stage Ah0(t+1)
        RDA(0, 1, 0); STAGE(1, 0, 0, t + 1);
        BARX; LGK0; MM(1); BARX;
        // ph2: read A(t) mh0 k1 + B(t) k1 | stage Ah1(t+1)
        RDA(0, 0, 1); RDB(0, 1); STAGE(1, 0, 1, t + 1);
        BARX; LGK0; MM(0); BARX;
        // ph3: read A(t) mh1 k1 | stage Bh0(t+2) | vmcnt -> (t+1) complete
        RDA(0, 1, 1); if (pre) STAGE(0, 1, 0, t + 2);
        BARX; LGK0; MM(1); VMC2; BARX;
        // ph4: read A(t+1) mh0 k0 + B(t+1) k0 | stage Bh1(t+2)
        RDA(1, 0, 0); RDB(1, 0); if (pre) STAGE(0, 1, 1, t + 2);
        BARX; LGK0; MM(0); BARX;
        // ph5: read A(t+1) mh1 k0 | stage Ah0(t+2)
        RDA(1, 1, 0); if (pre) STAGE(0, 0, 0, t + 2);
        BARX; LGK0; MM(1); BARX;
        // ph6: read A(t+1) mh0 k1 + B(t+1) k1 | stage Ah1(t+2)
        RDA(1, 0, 1); RDB(1, 1); if (pre) STAGE(0, 0, 1, t + 2);
        BARX; LGK0; MM(0); BARX;
        // ph7: read A(t+1) mh1 k1 | stage Bh0(t+3) | vmcnt -> (t+2) complete
        RDA(1, 1, 1); if (pre) STAGE(1, 1, 0, t + 3);
        BARX; LGK0; MM(1); VMC2; BARX;
    }
#undef BARX
#undef LGK0
#undef VMC2

    // epilogue
    const float* biasg = jb.bias + (size_t)(jb.routed ? (rt[m0 >> 10]) : 0) * NE;
#pragma unroll
    for (int am = 0; am < 8; ++am) {
        int row = m0 + wm * 128 + am * 16 + g4 * 4;
#pragma unroll
        for (int nf = 0; nf < 4; ++nf) {
            int col = n0 + wn * 64 + nf * 16 + frow;
            float bv = biasg[col];
            f32x4 v = acc[am][nf];
#pragma unroll
            for (int r = 0; r < 4; ++r) {
                float val = (v[r] + bv) * jb.scale;
                if (OUT_F32)
                    ((float*)jb.out)[(size_t)(row + r) * NE + col] = val;
                else
                    ((unsigned short*)jb.out)[(size_t)(row + r) * NE + col] = f2bf(val);
            }
        }
    }
}

// ---------------- V transpose: Vt[(b,h),d,s] = V[b,s,h*64+d] ----------------
__global__ void k_vtrans(const unsigned short* __restrict__ V, unsigned short* __restrict__ Vt) {
    __shared__ unsigned short tile[64][65];
    const int blk = blockIdx.x;
    const int bh = blk >> 4;
    const int b = bh >> 4;
    const int h = bh & 15;
    const int s0 = (blk & 15) * 64;
    const int tid = threadIdx.x;
#pragma unroll
    for (int i = 0; i < 2; ++i) {
        int seg = tid + i * 256;
        int row = seg >> 3;
        int c8 = (seg & 7) * 8;
        const unsigned short* src = V + (size_t)(b * NT + s0 + row) * NE + h * 64 + c8;
        ushort4 u0 = *reinterpret_cast<const ushort4*>(src);
        ushort4 u1 = *reinterpret_cast<const ushort4*>(src + 4);
        tile[row][c8 + 0] = u0.x; tile[row][c8 + 1] = u0.y;
        tile[row][c8 + 2] = u0.z; tile[row][c8 + 3] = u0.w;
        tile[row][c8 + 4] = u1.x; tile[row][c8 + 5] = u1.y;
        tile[row][c8 + 6] = u1.z; tile[row][c8 + 7] = u1.w;
    }
    __syncthreads();
#pragma unroll
    for (int i = 0; i < 2; ++i) {
        int seg = tid + i * 256;
        int drow = seg >> 3;
        int s8 = (seg & 7) * 8;
        ushort4 u0, u1;
        u0.x = tile[s8 + 0][drow]; u0.y = tile[s8 + 1][drow];
        u0.z = tile[s8 + 2][drow]; u0.w = tile[s8 + 3][drow];
        u1.x = tile[s8 + 4][drow]; u1.y = tile[s8 + 5][drow];
        u1.z = tile[s8 + 6][drow]; u1.w = tile[s8 + 7][drow];
        unsigned short* dst = Vt + (size_t)(bh * 64 + drow) * NT + s0 + s8;
        *reinterpret_cast<ushort4*>(dst) = u0;
        *reinterpret_cast<ushort4*>(dst + 4) = u1;
    }
}

// ---------------- fused dual-stream attention, LDS-staged K/Kr/V ------------
// (unchanged from R3 — next round's target)
__global__ void k_attn(const unsigned short* __restrict__ Q,
                       const unsigned short* __restrict__ K,
                       const unsigned short* __restrict__ Qr,
                       const unsigned short* __restrict__ Kr,
                       const unsigned short* __restrict__ Vt,
                       unsigned short* __restrict__ attnO)
{
    constexpr int PLD = 40;
    __shared__ __attribute__((aligned(16))) unsigned short KV[2][6144];   // Kg|Kr|V, 12KB each
    __shared__ __attribute__((aligned(16))) unsigned short Pg[8][16 * PLD];
    __shared__ __attribute__((aligned(16))) unsigned short Pr[8][16 * PLD];

    const int blk = (blockIdx.x & 7) * 128 + (blockIdx.x >> 3);
    const int tile = blk & 7;
    const int bh = blk >> 3;
    const int b = bh >> 4;
    const int h = bh & 15;
    const int wid = threadIdx.x >> 6;
    const int lane = threadIdx.x & 63;
    const int frow = lane & 15;
    const int g4 = lane >> 4;
    const int fk8 = g4 * 8;
    const int t0 = tile * 128 + wid * 16;

    const size_t qoff = (size_t)(b * NT + t0 + frow) * NE + h * 64;
    const bf16x8 qf0 = *reinterpret_cast<const bf16x8*>(Q + qoff + fk8);
    const bf16x8 qf1 = *reinterpret_cast<const bf16x8*>(Q + qoff + 32 + fk8);
    const bf16x8 qr0 = *reinterpret_cast<const bf16x8*>(Qr + qoff + fk8);
    const bf16x8 qr1 = *reinterpret_cast<const bf16x8*>(Qr + qoff + 32 + fk8);

    const unsigned short* Kb  = K  + (size_t)b * NT * NE + h * 64;
    const unsigned short* Krb = Kr + (size_t)b * NT * NE + h * 64;
    const unsigned short* Vtb = Vt + (size_t)bh * 64 * NT;
    unsigned short* Pgw = &Pg[wid][0];
    unsigned short* Prw = &Pr[wid][0];

    f32x4 og[4], orr[4];
    float lgp[4], lrp[4];
#pragma unroll
    for (int i = 0; i < 4; ++i) {
        og[i] = (f32x4){0.f, 0.f, 0.f, 0.f};
        orr[i] = (f32x4){0.f, 0.f, 0.f, 0.f};
        lgp[i] = 0.f; lrp[i] = 0.f;
    }

    auto stage = [&](int buf, int s0) {
#pragma unroll
        for (int i = 0; i < 2; ++i) {
            int cg = (i == 0) ? wid : (8 + wid);
            if (i == 1 && wid >= 4) break;
            int c = cg * 64 + lane;
            const unsigned short* src;
            if (cg < 8) {
                const unsigned short* base = (cg < 4) ? Kb : Krb;
                int cc = c & 255;
                int row = cc >> 3, cb = cc & 7;
                src = base + (size_t)(s0 + row) * NE + ((cb ^ (row & 7)) * 8);
            } else {
                int cc = c - 512;
                int d = cc >> 2, cb = cc & 3;
                src = Vtb + (size_t)d * NT + s0 + ((cb ^ (d & 3)) * 8);
            }
            __builtin_amdgcn_global_load_lds((AS1 void*)src, (AS3 void*)(&KV[buf][cg * 512]), 16, 0, 0);
        }
    };

    stage(0, 0);
    __syncthreads();
    int cur = 0;
    for (int t = 0; t < NT / 32; ++t) {
        if (t + 1 < NT / 32) stage(cur ^ 1, (t + 1) * 32);

        const unsigned short* Kl  = &KV[cur][0];
        const unsigned short* Krl = &KV[cur][2048];
        const unsigned short* Vl  = &KV[cur][4096];
        bf16x8 kg[2][2], kr[2][2], vb[4];
#pragma unroll
        for (int nf = 0; nf < 2; ++nf)
#pragma unroll
            for (int kh = 0; kh < 2; ++kh) {
                int idx = (nf * 16 + frow) * 64 + (((g4 + 4 * kh) ^ (frow & 7)) * 8);
                kg[nf][kh] = *reinterpret_cast<const bf16x8*>(Kl + idx);
                kr[nf][kh] = *reinterpret_cast<const bf16x8*>(Krl + idx);
            }
#pragma unroll
        for (int nf2 = 0; nf2 < 4; ++nf2)
            vb[nf2] = *reinterpret_cast<const bf16x8*>(Vl + (nf2 * 16 + frow) * 32 + ((g4 ^ (frow & 3)) * 8));

        const f32x4 z = (f32x4){0.f, 0.f, 0.f, 0.f};
        f32x4 sg0 = __builtin_amdgcn_mfma_f32_16x16x32_bf16(qf0, kg[0][0], z, 0, 0, 0);
        f32x4 sg1 = __builtin_amdgcn_mfma_f32_16x16x32_bf16(qf0, kg[1][0], z, 0, 0, 0);
        f32x4 sr0 = __builtin_amdgcn_mfma_f32_16x16x32_bf16(qr0, kr[0][0], z, 0, 0, 0);
        f32x4 sr1 = __builtin_amdgcn_mfma_f32_16x16x32_bf16(qr0, kr[1][0], z, 0, 0, 0);
        sg0 = __builtin_amdgcn_mfma_f32_16x16x32_bf16(qf1, kg[0][1], sg0, 0, 0, 0);
        sg1 = __builtin_amdgcn_mfma_f32_16x16x32_bf16(qf1, kg[1][1], sg1, 0, 0, 0);
        sr0 = __builtin_amdgcn_mfma_f32_16x16x32_bf16(qr1, kr[0][1], sr0, 0, 0, 0);
        sr1 = __builtin_amdgcn_mfma_f32_16x16x32_bf16(qr1, kr[1][1], sr1, 0, 0, 0);

#pragma unroll
        for (int r = 0; r < 4; ++r) {
            float pg0 = __expf(sg0[r]);
            float pg1 = __expf(sg1[r]);
            float pr0 = __expf(sr0[r]);
            float pr1 = __expf(sr1[r]);
            lgp[r] += pg0 + pg1;
            lrp[r] += pr0 + pr1;
            const int row = (g4 * 4 + r) * PLD;
            Pgw[row + frow]      = f2bfu(pg0);
            Pgw[row + 16 + frow] = f2bfu(pg1);
            Prw[row + frow]      = f2bfu(pr0);
            Prw[row + 16 + frow] = f2bfu(pr1);
        }
        asm volatile("s_waitcnt lgkmcnt(0)" ::: "memory");
        bf16x8 pag = *reinterpret_cast<const bf16x8*>(Pgw + frow * PLD + fk8);
        bf16x8 par = *reinterpret_cast<const bf16x8*>(Prw + frow * PLD + fk8);
        og[0]  = __builtin_amdgcn_mfma_f32_16x16x32_bf16(pag, vb[0], og[0], 0, 0, 0);
        orr[0] = __builtin_amdgcn_mfma_f32_16x16x32_bf16(par, vb[0], orr[0], 0, 0, 0);
        og[1]  = __builtin_amdgcn_mfma_f32_16x16x32_bf16(pag, vb[1], og[1], 0, 0, 0);
        orr[1] = __builtin_amdgcn_mfma_f32_16x16x32_bf16(par, vb[1], orr[1], 0, 0, 0);
        og[2]  = __builtin_amdgcn_mfma_f32_16x16x32_bf16(pag, vb[2], og[2], 0, 0, 0);
        orr[2] = __builtin_amdgcn_mfma_f32_16x16x32_bf16(par, vb[2], orr[2], 0, 0, 0);
        og[3]  = __builtin_amdgcn_mfma_f32_16x16x32_bf16(pag, vb[3], og[3], 0, 0, 0);
        orr[3] = __builtin_amdgcn_mfma_f32_16x16x32_bf16(par, vb[3], orr[3], 0, 0, 0);

        __syncthreads();
        cur ^= 1;
    }

#pragma unroll
    for (int off = 1; off <= 8; off <<= 1) {
#pragma unroll
        for (int r = 0; r < 4; ++r) {
            lgp[r] += __shfl_xor(lgp[r], off);
            lrp[r] += __shfl_xor(lrp[r], off);
        }
    }
    float ig[4], ir[4];
#pragma unroll
    for (int r = 0; r < 4; ++r) { ig[r] = 0.45f / lgp[r]; ir[r] = 0.05f / lrp[r]; }
#pragma unroll
    for (int nf2 = 0; nf2 < 4; ++nf2) {
#pragma unroll
        for (int r = 0; r < 4; ++r) {
            float val = og[nf2][r] * ig[r] + orr[nf2][r] * ir[r];
            int t = t0 + g4 * 4 + r;
            attnO[(size_t)(b * NT + t) * NE + h * 64 + nf2 * 16 + frow] = f2bf(val);
        }
    }
}

// ---------------- launcher ----------------
extern "C" void kernel_launch(void* const* d_in, const int* in_sizes, int n_in,
                              void* d_out, int out_size, void* d_ws, size_t ws_size,
                              hipStream_t stream)
{
    const float* hs  = (const float*)d_in[0];
    const int*   rt  = (const int*)d_in[1];
    const float* Wq  = (const float*)d_in[2];
    const float* bq  = (const float*)d_in[3];
    const float* Wk  = (const float*)d_in[4];
    const float* bk  = (const float*)d_in[5];
    const float* Wv  = (const float*)d_in[6];
    const float* bv  = (const float*)d_in[7];
    const float* Wo  = (const float*)d_in[8];
    const float* bo  = (const float*)d_in[9];
    const float* RWq = (const float*)d_in[10];
    const float* Rbq = (const float*)d_in[11];
    const float* RWk = (const float*)d_in[12];
    const float* Rbk = (const float*)d_in[13];

    unsigned short* w = (unsigned short*)d_ws;
    const size_t NBT = (size_t)BT * NE;   // 8M elems
    const size_t NW  = (size_t)NE * NE;   // 1M elems
    unsigned short* hsB  = w; w += NBT;
    unsigned short* Qb   = w; w += NBT;
    unsigned short* Kb   = w; w += NBT;
    unsigned short* Vb   = w; w += NBT;
    unsigned short* Qrb  = w; w += NBT;
    unsigned short* Krb  = w; w += NBT;
    unsigned short* Vtb  = w; w += NBT;
    unsigned short* atb  = w; w += NBT;
    unsigned short* WqB  = w; w += NW;
    unsigned short* WkB  = w; w += NW;
    unsigned short* WvB  = w; w += NW;
    unsigned short* WoB  = w; w += NW;
    unsigned short* RWqB = w; w += 4 * NW;
    unsigned short* RWkB = w; w += 4 * NW;

    k_cvt<<<dim3((unsigned)(NBT / 1024)), dim3(256), 0, stream>>>(hs, hsB, (int)NBT);
    k_cvt<<<dim3((unsigned)(NW / 1024)), dim3(256), 0, stream>>>(Wq, WqB, (int)NW);
    k_cvt<<<dim3((unsigned)(NW / 1024)), dim3(256), 0, stream>>>(Wk, WkB, (int)NW);
    k_cvt<<<dim3((unsigned)(NW / 1024)), dim3(256), 0, stream>>>(Wv, WvB, (int)NW);
    k_cvt<<<dim3((unsigned)(NW / 1024)), dim3(256), 0, stream>>>(Wo, WoB, (int)NW);
    k_cvt<<<dim3((unsigned)(4 * NW / 1024)), dim3(256), 0, stream>>>(RWq, RWqB, (int)(4 * NW));
    k_cvt<<<dim3((unsigned)(4 * NW / 1024)), dim3(256), 0, stream>>>(RWk, RWkB, (int)(4 * NW));

    // fused 5-projection GEMM: 5 x (32 x 4) blocks, z selects job
    GJob jq  = { WqB,  bq,  Qb,  0.125f, 0 };
    GJob jk  = { WkB,  bk,  Kb,  1.0f,   0 };
    GJob jv  = { WvB,  bv,  Vb,  1.0f,   0 };
    GJob jrq = { RWqB, Rbq, Qrb, 0.125f, 1 };
    GJob jrk = { RWkB, Rbk, Krb, 1.0f,   1 };
    k_gemm256<false><<<dim3(640), dim3(512), 0, stream>>>(hsB, jq, jk, jv, jrq, jrk, rt, 80);

    k_vtrans<<<dim3(NB * NH * 16), dim3(256), 0, stream>>>(Vb, Vtb);
    k_attn<<<dim3(NB * NH * 8), dim3(512), 0, stream>>>(Qb, Kb, Qrb, Krb, Vtb, atb);

    GJob jo = { WoB, bo, d_out, 1.0f, 0 };
    k_gemm256<true><<<dim3(128), dim3(512), 0, stream>>>(atb, jo, jo, jo, jo, jo, nullptr, 16);
}

// Round 6
// 262.546 us; speedup vs baseline: 2.1400x; 1.0463x over previous
//
#include <hip/hip_runtime.h>
#include <stdint.h>

#define AS1 __attribute__((address_space(1)))
#define AS3 __attribute__((address_space(3)))

typedef __attribute__((ext_vector_type(8))) short bf16x8;   // 8 bf16 = 4 VGPRs
typedef __attribute__((ext_vector_type(4))) float f32x4;

#define NB 8
#define NT 1024
#define NE 1024
#define NH 16
#define BT (NB * NT)

__device__ __forceinline__ unsigned short f2bf(float f) {
    unsigned int u = __builtin_bit_cast(unsigned int, f);
    u += 0x7FFFu + ((u >> 16) & 1u);          // RNE
    return (unsigned short)(u >> 16);
}
// pack two f32 -> one u32 of 2 bf16 (RNE) in a single VALU op
__device__ __forceinline__ unsigned int cvt_pk_bf16(float lo, float hi) {
    unsigned int r;
    asm("v_cvt_pk_bf16_f32 %0, %1, %2" : "=v"(r) : "v"(lo), "v"(hi));
    return r;
}

// ---------------- fused f32 -> bf16 conversion, 7 segments ----------------
__global__ void k_cvt7(const float* __restrict__ hs, unsigned short* __restrict__ hsB,
                       const float* __restrict__ w1, unsigned short* __restrict__ w1B,
                       const float* __restrict__ w2, unsigned short* __restrict__ w2B,
                       const float* __restrict__ w3, unsigned short* __restrict__ w3B,
                       const float* __restrict__ w4, unsigned short* __restrict__ w4B,
                       const float* __restrict__ r1, unsigned short* __restrict__ r1B,
                       const float* __restrict__ r2, unsigned short* __restrict__ r2B)
{
    int blk = blockIdx.x;
    const float* s; unsigned short* d; int base;
    if      (blk < 8192)  { s = hs; d = hsB; base = 0; }
    else if (blk < 9216)  { s = w1; d = w1B; base = 8192; }
    else if (blk < 10240) { s = w2; d = w2B; base = 9216; }
    else if (blk < 11264) { s = w3; d = w3B; base = 10240; }
    else if (blk < 12288) { s = w4; d = w4B; base = 11264; }
    else if (blk < 16384) { s = r1; d = r1B; base = 12288; }
    else                  { s = r2; d = r2B; base = 16384; }
    int i = ((blk - base) * 256 + threadIdx.x) * 4;
    float4 f = *reinterpret_cast<const float4*>(s + i);
    ushort4 o;
    o.x = f2bf(f.x); o.y = f2bf(f.y); o.z = f2bf(f.z); o.w = f2bf(f.w);
    *reinterpret_cast<ushort4*>(d + i) = o;
}

// ============ 256x256 8-phase GEMM (T2+T3+T4+T5), C = A·W^T + bias =========
struct GJob {
    const unsigned short* W;
    const float* bias;
    void* out;
    float scale;
    int routed;
};

template <bool OUT_F32>
__global__ __launch_bounds__(512, 2)
void k_gemm256(const unsigned short* __restrict__ A,
               GJob j0, GJob j1, GJob j2, GJob j3, GJob j4,
               const int* __restrict__ rt, int cpx)
{
    __shared__ __attribute__((aligned(16))) unsigned short LB[2][2][2][128 * 64];

    const int flat = blockIdx.x;
    const int wgid = (flat & 7) * cpx + (flat >> 3);   // XCD-chunked, nwg%8==0
    const int pz  = wgid >> 7;
    const int rem = wgid & 127;
    const int by = rem >> 2, bx = rem & 3;
    const int m0 = by << 8, n0 = bx << 8;

    GJob jb = j0;
    if (pz == 1) jb = j1;
    else if (pz == 2) jb = j2;
    else if (pz == 3) jb = j3;
    else if (pz == 4) jb = j4;
    int g = jb.routed ? rt[m0 >> 10] : 0;
    const unsigned short* Wg = jb.W + (size_t)g * NE * NE;

    const int tid  = threadIdx.x;
    const int wid  = tid >> 6;
    const int lane = tid & 63;
    const int frow = lane & 15;
    const int g4   = lane >> 4;
    const int wm = wid >> 2, wn = wid & 3;

    const int rh0  = tid >> 3;
    const int swz8 = ((tid & 7) ^ (rh0 & 7)) * 8;
    const unsigned short* baseA = A  + (size_t)m0 * NE;
    const unsigned short* baseB = Wg + (size_t)n0 * NE;

    auto STAGE = [&](int d, int mat, int half, int kt) {
        const unsigned short* base = mat ? baseB : baseA;
#pragma unroll
        for (int j = 0; j < 2; ++j) {
            const unsigned short* src =
                base + (size_t)(half * 128 + rh0 + j * 64) * NE + kt * 64 + swz8;
            __builtin_amdgcn_global_load_lds((AS1 void*)src,
                (AS3 void*)&LB[d][mat][half][(wid * 64 + j * 512) * 8], 16, 0, 0);
        }
    };

    f32x4 acc[8][4];
#pragma unroll
    for (int m = 0; m < 8; ++m)
#pragma unroll
        for (int n = 0; n < 4; ++n) acc[m][n] = (f32x4){0.f, 0.f, 0.f, 0.f};

    bf16x8 a4[4], b4[4];
    auto RDA = [&](int d, int mh, int kh) {
#pragma unroll
        for (int mf = 0; mf < 4; ++mf) {
            int rh = mh * 64 + mf * 16 + frow;
            int off = rh * 64 + (((kh * 4 + g4) ^ (frow & 7)) * 8);
            a4[mf] = *reinterpret_cast<const bf16x8*>(&LB[d][0][wm][off]);
        }
    };
    auto RDB = [&](int d, int kh) {
#pragma unroll
        for (int nf = 0; nf < 4; ++nf) {
            int rh = (wn & 1) * 64 + nf * 16 + frow;
            int off = rh * 64 + (((kh * 4 + g4) ^ (frow & 7)) * 8);
            b4[nf] = *reinterpret_cast<const bf16x8*>(&LB[d][1][wn >> 1][off]);
        }
    };
    auto MM = [&](int mh) {
        __builtin_amdgcn_s_setprio(1);
#pragma unroll
        for (int mf = 0; mf < 4; ++mf)
#pragma unroll
            for (int nf = 0; nf < 4; ++nf)
                acc[mh * 4 + mf][nf] =
                    __builtin_amdgcn_mfma_f32_16x16x32_bf16(a4[mf], b4[nf], acc[mh * 4 + mf][nf], 0, 0, 0);
        __builtin_amdgcn_s_setprio(0);
    };

#define BARX __builtin_amdgcn_s_barrier()
#define LGK0 asm volatile("s_waitcnt lgkmcnt(0)" ::: "memory")
#define VMC2 asm volatile("s_waitcnt vmcnt(2)" ::: "memory")

    STAGE(0, 0, 0, 0); STAGE(0, 0, 1, 0); STAGE(0, 1, 0, 0); STAGE(0, 1, 1, 0);
    STAGE(1, 1, 0, 1);
    VMC2; BARX;

#pragma unroll 1
    for (int i = 0; i < 8; ++i) {
        const int t = 2 * i;
        const bool pre = (i < 7);
        RDA(0, 0, 0); RDB(0, 0); STAGE(1, 1, 1, t + 1);
        BARX; LGK0; MM(0); BARX;
        RDA(0, 1, 0); STAGE(1, 0, 0, t + 1);
        BARX; LGK0; MM(1); BARX;
        RDA(0, 0, 1); RDB(0, 1); STAGE(1, 0, 1, t + 1);
        BARX; LGK0; MM(0); BARX;
        RDA(0, 1, 1); if (pre) STAGE(0, 1, 0, t + 2);
        BARX; LGK0; MM(1); VMC2; BARX;
        RDA(1, 0, 0); RDB(1, 0); if (pre) STAGE(0, 1, 1, t + 2);
        BARX; LGK0; MM(0); BARX;
        RDA(1, 1, 0); if (pre) STAGE(0, 0, 0, t + 2);
        BARX; LGK0; MM(1); BARX;
        RDA(1, 0, 1); RDB(1, 1); if (pre) STAGE(0, 0, 1, t + 2);
        BARX; LGK0; MM(0); BARX;
        RDA(1, 1, 1); if (pre) STAGE(1, 1, 0, t + 3);
        BARX; LGK0; MM(1); VMC2; BARX;
    }
#undef BARX
#undef LGK0
#undef VMC2

    const float* biasg = jb.bias + (size_t)(jb.routed ? (rt[m0 >> 10]) : 0) * NE;
#pragma unroll
    for (int am = 0; am < 8; ++am) {
        int row = m0 + wm * 128 + am * 16 + g4 * 4;
#pragma unroll
        for (int nf = 0; nf < 4; ++nf) {
            int col = n0 + wn * 64 + nf * 16 + frow;
            float bv = biasg[col];
            f32x4 v = acc[am][nf];
#pragma unroll
            for (int r = 0; r < 4; ++r) {
                float val = (v[r] + bv) * jb.scale;
                if (OUT_F32)
                    ((float*)jb.out)[(size_t)(row + r) * NE + col] = val;
                else
                    ((unsigned short*)jb.out)[(size_t)(row + r) * NE + col] = f2bf(val);
            }
        }
    }
}

// ---------------- V transpose: Vt[(b,h),d,s] = V[b,s,h*64+d] ----------------
__global__ void k_vtrans(const unsigned short* __restrict__ V, unsigned short* __restrict__ Vt) {
    __shared__ unsigned short tile[64][65];
    const int blk = blockIdx.x;
    const int bh = blk >> 4;
    const int b = bh >> 4;
    const int h = bh & 15;
    const int s0 = (blk & 15) * 64;
    const int tid = threadIdx.x;
#pragma unroll
    for (int i = 0; i < 2; ++i) {
        int seg = tid + i * 256;
        int row = seg >> 3;
        int c8 = (seg & 7) * 8;
        const unsigned short* src = V + (size_t)(b * NT + s0 + row) * NE + h * 64 + c8;
        ushort4 u0 = *reinterpret_cast<const ushort4*>(src);
        ushort4 u1 = *reinterpret_cast<const ushort4*>(src + 4);
        tile[row][c8 + 0] = u0.x; tile[row][c8 + 1] = u0.y;
        tile[row][c8 + 2] = u0.z; tile[row][c8 + 3] = u0.w;
        tile[row][c8 + 4] = u1.x; tile[row][c8 + 5] = u1.y;
        tile[row][c8 + 6] = u1.z; tile[row][c8 + 7] = u1.w;
    }
    __syncthreads();
#pragma unroll
    for (int i = 0; i < 2; ++i) {
        int seg = tid + i * 256;
        int drow = seg >> 3;
        int s8 = (seg & 7) * 8;
        ushort4 u0, u1;
        u0.x = tile[s8 + 0][drow]; u0.y = tile[s8 + 1][drow];
        u0.z = tile[s8 + 2][drow]; u0.w = tile[s8 + 3][drow];
        u1.x = tile[s8 + 4][drow]; u1.y = tile[s8 + 5][drow];
        u1.z = tile[s8 + 6][drow]; u1.w = tile[s8 + 7][drow];
        unsigned short* dst = Vt + (size_t)(bh * 64 + drow) * NT + s0 + s8;
        *reinterpret_cast<ushort4*>(dst) = u0;
        *reinterpret_cast<ushort4*>(dst + 4) = u1;
    }
}

// ---------------- fused dual-stream attention, swapped-QK^T ------------------
// 8 waves x 16 q-rows; KVBLK=64; LDS-staged K/Kr/V (dbuf, chunk-XOR swizzle).
// Swapped QK (mfma(K,Q) -> S^T): lane holds P for q-row frow -> contiguous
// b64 P-writes, cvt_pk packs, scalar per-lane l. Stream-serial P buffer.
// No-max exp accumulation (scores bounded; exp(-m) cancels in O/l).
__global__ __launch_bounds__(512, 4)
void k_attn(const unsigned short* __restrict__ Q,
            const unsigned short* __restrict__ K,
            const unsigned short* __restrict__ Qr,
            const unsigned short* __restrict__ Kr,
            const unsigned short* __restrict__ Vt,
            unsigned short* __restrict__ attnO)
{
    constexpr int PLD = 72;   // 144B rows: 16B-aligned b128 reads, 2-way max banks
    __shared__ __attribute__((aligned(16))) unsigned short KV[2][3 * 4096];   // Kg|Kr|V 8KB each
    __shared__ __attribute__((aligned(16))) unsigned short Ps[8][16 * PLD];   // per-wave P (serial)

    // bijective XCD swizzle: all 8 blocks of one head on one XCD
    const int blk = (blockIdx.x & 7) * 128 + (blockIdx.x >> 3);
    const int tile = blk & 7;
    const int bh = blk >> 3;
    const int b = bh >> 4;
    const int h = bh & 15;
    const int wid = threadIdx.x >> 6;
    const int lane = threadIdx.x & 63;
    const int frow = lane & 15;
    const int g4 = lane >> 4;
    const int f7 = frow & 7;
    const int fk8 = g4 * 8;
    const int t0 = tile * 128 + wid * 16;

    const size_t qoff = (size_t)(b * NT + t0 + frow) * NE + h * 64;
    const bf16x8 qf0 = *reinterpret_cast<const bf16x8*>(Q + qoff + fk8);
    const bf16x8 qf1 = *reinterpret_cast<const bf16x8*>(Q + qoff + 32 + fk8);
    const bf16x8 qr0 = *reinterpret_cast<const bf16x8*>(Qr + qoff + fk8);
    const bf16x8 qr1 = *reinterpret_cast<const bf16x8*>(Qr + qoff + 32 + fk8);

    const unsigned short* Kb  = K  + (size_t)b * NT * NE + h * 64;
    const unsigned short* Krb = Kr + (size_t)b * NT * NE + h * 64;
    const unsigned short* Vtb = Vt + (size_t)bh * 64 * NT;
    unsigned short* Pw = &Ps[wid][0];
    unsigned short* Prow = Pw + frow * PLD;

    f32x4 og[4], orr[4];
    float lgp = 0.f, lrp = 0.f;
#pragma unroll
    for (int i = 0; i < 4; ++i) {
        og[i] = (f32x4){0.f, 0.f, 0.f, 0.f};
        orr[i] = (f32x4){0.f, 0.f, 0.f, 0.f};
    }

    // staging: 64 rows x 8 chunks per 8KB section; chunk (row,cb) holds
    // src[row][8*(cb ^ (row&7)) ..+8]; LDS dest linear (wave-uniform + lane*16)
    const int srow = threadIdx.x >> 3;                         // 0..63
    const int scb8 = ((threadIdx.x & 7) ^ (srow & 7)) * 8;
    auto stage = [&](int buf, int s0) {
        const unsigned short* sK = Kb  + (size_t)(s0 + srow) * NE + scb8;
        const unsigned short* sR = Krb + (size_t)(s0 + srow) * NE + scb8;
        const unsigned short* sV = Vtb + (size_t)srow * NT + s0 + scb8;
        __builtin_amdgcn_global_load_lds((AS1 void*)sK, (AS3 void*)(&KV[buf][wid * 512]), 16, 0, 0);
        __builtin_amdgcn_global_load_lds((AS1 void*)sR, (AS3 void*)(&KV[buf][4096 + wid * 512]), 16, 0, 0);
        __builtin_amdgcn_global_load_lds((AS1 void*)sV, (AS3 void*)(&KV[buf][8192 + wid * 512]), 16, 0, 0);
    };

    stage(0, 0);
    __syncthreads();
    int cur = 0;
    const f32x4 z = (f32x4){0.f, 0.f, 0.f, 0.f};
#pragma unroll 1
    for (int t = 0; t < NT / 64; ++t) {
        if (t < NT / 64 - 1) stage(cur ^ 1, (t + 1) * 64);
        const unsigned short* Kl  = &KV[cur][0];
        const unsigned short* Krl = &KV[cur][4096];
        const unsigned short* Vl  = &KV[cur][8192];

        // QK^T swapped: sg[nf] lane = S[q=frow][s=16nf+4g4+r]
        f32x4 sg[4], sr[4];
#pragma unroll
        for (int nf = 0; nf < 4; ++nf) {
            const int ro = (nf * 16 + frow) * 64;
            bf16x8 kA = *reinterpret_cast<const bf16x8*>(Kl + ro + ((g4 ^ f7) * 8));
            bf16x8 kB = *reinterpret_cast<const bf16x8*>(Kl + ro + (((4 + g4) ^ f7) * 8));
            bf16x8 rA = *reinterpret_cast<const bf16x8*>(Krl + ro + ((g4 ^ f7) * 8));
            bf16x8 rB = *reinterpret_cast<const bf16x8*>(Krl + ro + (((4 + g4) ^ f7) * 8));
            sg[nf] = __builtin_amdgcn_mfma_f32_16x16x32_bf16(kA, qf0, z, 0, 0, 0);
            sg[nf] = __builtin_amdgcn_mfma_f32_16x16x32_bf16(kB, qf1, sg[nf], 0, 0, 0);
            sr[nf] = __builtin_amdgcn_mfma_f32_16x16x32_bf16(rA, qr0, z, 0, 0, 0);
            sr[nf] = __builtin_amdgcn_mfma_f32_16x16x32_bf16(rB, qr1, sr[nf], 0, 0, 0);
        }

        // ---- generic stream: exp, pack, P-transpose via LDS, PV ----
#pragma unroll
        for (int nf = 0; nf < 4; ++nf) {
            float p0 = __expf(sg[nf][0]), p1 = __expf(sg[nf][1]);
            float p2 = __expf(sg[nf][2]), p3 = __expf(sg[nf][3]);
            lgp += (p0 + p1) + (p2 + p3);
            uint2 wv;
            wv.x = cvt_pk_bf16(p0, p1);
            wv.y = cvt_pk_bf16(p2, p3);
            *reinterpret_cast<uint2*>(Prow + nf * 16 + g4 * 4) = wv;
        }
        asm volatile("s_waitcnt lgkmcnt(0)" ::: "memory");   // P visible (same wave)
        {
            bf16x8 pa0 = *reinterpret_cast<const bf16x8*>(Prow + fk8);
            bf16x8 pa1 = *reinterpret_cast<const bf16x8*>(Prow + 32 + fk8);
#pragma unroll
            for (int nf2 = 0; nf2 < 4; ++nf2) {
                const int vo = (nf2 * 16 + frow) * 64;
                bf16x8 v0 = *reinterpret_cast<const bf16x8*>(Vl + vo + ((g4 ^ f7) * 8));
                bf16x8 v1 = *reinterpret_cast<const bf16x8*>(Vl + vo + (((4 + g4) ^ f7) * 8));
                og[nf2] = __builtin_amdgcn_mfma_f32_16x16x32_bf16(pa0, v0, og[nf2], 0, 0, 0);
                og[nf2] = __builtin_amdgcn_mfma_f32_16x16x32_bf16(pa1, v1, og[nf2], 0, 0, 0);
            }
        }

        // ---- reader stream: reuse P buffer (DS pipe in-order per wave) ----
#pragma unroll
        for (int nf = 0; nf < 4; ++nf) {
            float p0 = __expf(sr[nf][0]), p1 = __expf(sr[nf][1]);
            float p2 = __expf(sr[nf][2]), p3 = __expf(sr[nf][3]);
            lrp += (p0 + p1) + (p2 + p3);
            uint2 wv;
            wv.x = cvt_pk_bf16(p0, p1);
            wv.y = cvt_pk_bf16(p2, p3);
            *reinterpret_cast<uint2*>(Prow + nf * 16 + g4 * 4) = wv;
        }
        asm volatile("s_waitcnt lgkmcnt(0)" ::: "memory");
        {
            bf16x8 pa0 = *reinterpret_cast<const bf16x8*>(Prow + fk8);
            bf16x8 pa1 = *reinterpret_cast<const bf16x8*>(Prow + 32 + fk8);
#pragma unroll
            for (int nf2 = 0; nf2 < 4; ++nf2) {
                const int vo = (nf2 * 16 + frow) * 64;
                bf16x8 v0 = *reinterpret_cast<const bf16x8*>(Vl + vo + ((g4 ^ f7) * 8));
                bf16x8 v1 = *reinterpret_cast<const bf16x8*>(Vl + vo + (((4 + g4) ^ f7) * 8));
                orr[nf2] = __builtin_amdgcn_mfma_f32_16x16x32_bf16(pa0, v0, orr[nf2], 0, 0, 0);
                orr[nf2] = __builtin_amdgcn_mfma_f32_16x16x32_bf16(pa1, v1, orr[nf2], 0, 0, 0);
            }
        }

        __syncthreads();   // drains vmcnt (next KV tile staged) + overwrite fence
        cur ^= 1;
    }

    // full row sums for q-row frow (reduce across the 4 g4 lanes)
    lgp += __shfl_xor(lgp, 16); lgp += __shfl_xor(lgp, 32);
    lrp += __shfl_xor(lrp, 16); lrp += __shfl_xor(lrp, 32);
    float ig = 0.45f / lgp, ir = 0.05f / lrp;
    // redistribute: output lane owns q-rows 4*g4+r; scales live at lane 4*g4+r
    float igr[4], irr[4];
#pragma unroll
    for (int r = 0; r < 4; ++r) {
        igr[r] = __shfl(ig, g4 * 4 + r);
        irr[r] = __shfl(ir, g4 * 4 + r);
    }
#pragma unroll
    for (int nf2 = 0; nf2 < 4; ++nf2) {
#pragma unroll
        for (int r = 0; r < 4; ++r) {
            float val = og[nf2][r] * igr[r] + orr[nf2][r] * irr[r];
            int tq = t0 + g4 * 4 + r;
            attnO[(size_t)(b * NT + tq) * NE + h * 64 + nf2 * 16 + frow] = f2bf(val);
        }
    }
}

// ---------------- launcher ----------------
extern "C" void kernel_launch(void* const* d_in, const int* in_sizes, int n_in,
                              void* d_out, int out_size, void* d_ws, size_t ws_size,
                              hipStream_t stream)
{
    const float* hs  = (const float*)d_in[0];
    const int*   rt  = (const int*)d_in[1];
    const float* Wq  = (const float*)d_in[2];
    const float* bq  = (const float*)d_in[3];
    const float* Wk  = (const float*)d_in[4];
    const float* bk  = (const float*)d_in[5];
    const float* Wv  = (const float*)d_in[6];
    const float* bv  = (const float*)d_in[7];
    const float* Wo  = (const float*)d_in[8];
    const float* bo  = (const float*)d_in[9];
    const float* RWq = (const float*)d_in[10];
    const float* Rbq = (const float*)d_in[11];
    const float* RWk = (const float*)d_in[12];
    const float* Rbk = (const float*)d_in[13];

    unsigned short* w = (unsigned short*)d_ws;
    const size_t NBT = (size_t)BT * NE;   // 8M elems
    const size_t NW  = (size_t)NE * NE;   // 1M elems
    unsigned short* hsB  = w; w += NBT;
    unsigned short* Qb   = w; w += NBT;
    unsigned short* Kb   = w; w += NBT;
    unsigned short* Vb   = w; w += NBT;
    unsigned short* Qrb  = w; w += NBT;
    unsigned short* Krb  = w; w += NBT;
    unsigned short* Vtb  = w; w += NBT;
    unsigned short* atb  = w; w += NBT;
    unsigned short* WqB  = w; w += NW;
    unsigned short* WkB  = w; w += NW;
    unsigned short* WvB  = w; w += NW;
    unsigned short* WoB  = w; w += NW;
    unsigned short* RWqB = w; w += 4 * NW;
    unsigned short* RWkB = w; w += 4 * NW;

    k_cvt7<<<dim3(20480), dim3(256), 0, stream>>>(hs, hsB, Wq, WqB, Wk, WkB, Wv, WvB,
                                                  Wo, WoB, RWq, RWqB, RWk, RWkB);

    GJob jq  = { WqB,  bq,  Qb,  0.125f, 0 };
    GJob jk  = { WkB,  bk,  Kb,  1.0f,   0 };
    GJob jv  = { WvB,  bv,  Vb,  1.0f,   0 };
    GJob jrq = { RWqB, Rbq, Qrb, 0.125f, 1 };
    GJob jrk = { RWkB, Rbk, Krb, 1.0f,   1 };
    k_gemm256<false><<<dim3(640), dim3(512), 0, stream>>>(hsB, jq, jk, jv, jrq, jrk, rt, 80);

    k_vtrans<<<dim3(NB * NH * 16), dim3(256), 0, stream>>>(Vb, Vtb);
    k_attn<<<dim3(NB * NH * 8), dim3(512), 0, stream>>>(Qb, Kb, Qrb, Krb, Vtb, atb);

    GJob jo = { WoB, bo, d_out, 1.0f, 0 };
    k_gemm256<true><<<dim3(128), dim3(512), 0, stream>>>(atb, jo, jo, jo, jo, jo, nullptr, 16);
}

// Round 7
// 241.752 us; speedup vs baseline: 2.3240x; 1.0860x over previous
//
#include <hip/hip_runtime.h>
#include <stdint.h>

#define AS1 __attribute__((address_space(1)))
#define AS3 __attribute__((address_space(3)))

typedef __attribute__((ext_vector_type(8))) short bf16x8;   // 8 bf16 = 4 VGPRs
typedef __attribute__((ext_vector_type(4))) float f32x4;

#define NB 8
#define NT 1024
#define NE 1024
#define NH 16
#define BT (NB * NT)

__device__ __forceinline__ unsigned short f2bf(float f) {
    unsigned int u = __builtin_bit_cast(unsigned int, f);
    u += 0x7FFFu + ((u >> 16) & 1u);          // RNE
    return (unsigned short)(u >> 16);
}
// pack two f32 -> one u32 of 2 bf16 (RNE) in a single VALU op
__device__ __forceinline__ unsigned int cvt_pk_bf16(float lo, float hi) {
    unsigned int r;
    asm("v_cvt_pk_bf16_f32 %0, %1, %2" : "=v"(r) : "v"(lo), "v"(hi));
    return r;
}

// ---------------- fused f32 -> bf16 conversion, 7 segments ----------------
__global__ void k_cvt7(const float* __restrict__ hs, unsigned short* __restrict__ hsB,
                       const float* __restrict__ w1, unsigned short* __restrict__ w1B,
                       const float* __restrict__ w2, unsigned short* __restrict__ w2B,
                       const float* __restrict__ w3, unsigned short* __restrict__ w3B,
                       const float* __restrict__ w4, unsigned short* __restrict__ w4B,
                       const float* __restrict__ r1, unsigned short* __restrict__ r1B,
                       const float* __restrict__ r2, unsigned short* __restrict__ r2B)
{
    int blk = blockIdx.x;
    const float* s; unsigned short* d; int base;
    if      (blk < 8192)  { s = hs; d = hsB; base = 0; }
    else if (blk < 9216)  { s = w1; d = w1B; base = 8192; }
    else if (blk < 10240) { s = w2; d = w2B; base = 9216; }
    else if (blk < 11264) { s = w3; d = w3B; base = 10240; }
    else if (blk < 12288) { s = w4; d = w4B; base = 11264; }
    else if (blk < 16384) { s = r1; d = r1B; base = 12288; }
    else                  { s = r2; d = r2B; base = 16384; }
    int i = ((blk - base) * 256 + threadIdx.x) * 4;
    float4 f = *reinterpret_cast<const float4*>(s + i);
    ushort4 o;
    o.x = f2bf(f.x); o.y = f2bf(f.y); o.z = f2bf(f.z); o.w = f2bf(f.w);
    *reinterpret_cast<ushort4*>(d + i) = o;
}

// ============ 256x256 8-phase GEMM (T2+T3+T4+T5), C = A·W^T + bias =========
struct GJob {
    const unsigned short* W;
    const float* bias;
    void* out;
    float scale;
    int routed;
};

template <bool OUT_F32>
__global__ __launch_bounds__(512, 2)
void k_gemm256(const unsigned short* __restrict__ A,
               GJob j0, GJob j1, GJob j2, GJob j3, GJob j4,
               const int* __restrict__ rt, int cpx)
{
    __shared__ __attribute__((aligned(16))) unsigned short LB[2][2][2][128 * 64];

    const int flat = blockIdx.x;
    const int wgid = (flat & 7) * cpx + (flat >> 3);   // XCD-chunked, nwg%8==0
    const int pz  = wgid >> 7;
    const int rem = wgid & 127;
    const int by = rem >> 2, bx = rem & 3;
    const int m0 = by << 8, n0 = bx << 8;

    GJob jb = j0;
    if (pz == 1) jb = j1;
    else if (pz == 2) jb = j2;
    else if (pz == 3) jb = j3;
    else if (pz == 4) jb = j4;
    int g = jb.routed ? rt[m0 >> 10] : 0;
    const unsigned short* Wg = jb.W + (size_t)g * NE * NE;

    const int tid  = threadIdx.x;
    const int wid  = tid >> 6;
    const int lane = tid & 63;
    const int frow = lane & 15;
    const int g4   = lane >> 4;
    const int wm = wid >> 2, wn = wid & 3;

    const int rh0  = tid >> 3;
    const int swz8 = ((tid & 7) ^ (rh0 & 7)) * 8;
    const unsigned short* baseA = A  + (size_t)m0 * NE;
    const unsigned short* baseB = Wg + (size_t)n0 * NE;

    auto STAGE = [&](int d, int mat, int half, int kt) {
        const unsigned short* base = mat ? baseB : baseA;
#pragma unroll
        for (int j = 0; j < 2; ++j) {
            const unsigned short* src =
                base + (size_t)(half * 128 + rh0 + j * 64) * NE + kt * 64 + swz8;
            __builtin_amdgcn_global_load_lds((AS1 void*)src,
                (AS3 void*)&LB[d][mat][half][(wid * 64 + j * 512) * 8], 16, 0, 0);
        }
    };

    f32x4 acc[8][4];
#pragma unroll
    for (int m = 0; m < 8; ++m)
#pragma unroll
        for (int n = 0; n < 4; ++n) acc[m][n] = (f32x4){0.f, 0.f, 0.f, 0.f};

    bf16x8 a4[4], b4[4];
    auto RDA = [&](int d, int mh, int kh) {
#pragma unroll
        for (int mf = 0; mf < 4; ++mf) {
            int rh = mh * 64 + mf * 16 + frow;
            int off = rh * 64 + (((kh * 4 + g4) ^ (frow & 7)) * 8);
            a4[mf] = *reinterpret_cast<const bf16x8*>(&LB[d][0][wm][off]);
        }
    };
    auto RDB = [&](int d, int kh) {
#pragma unroll
        for (int nf = 0; nf < 4; ++nf) {
            int rh = (wn & 1) * 64 + nf * 16 + frow;
            int off = rh * 64 + (((kh * 4 + g4) ^ (frow & 7)) * 8);
            b4[nf] = *reinterpret_cast<const bf16x8*>(&LB[d][1][wn >> 1][off]);
        }
    };
    auto MM = [&](int mh) {
        __builtin_amdgcn_s_setprio(1);
#pragma unroll
        for (int mf = 0; mf < 4; ++mf)
#pragma unroll
            for (int nf = 0; nf < 4; ++nf)
                acc[mh * 4 + mf][nf] =
                    __builtin_amdgcn_mfma_f32_16x16x32_bf16(a4[mf], b4[nf], acc[mh * 4 + mf][nf], 0, 0, 0);
        __builtin_amdgcn_s_setprio(0);
    };

#define BARX __builtin_amdgcn_s_barrier()
#define LGK0 asm volatile("s_waitcnt lgkmcnt(0)" ::: "memory")
#define VMC2 asm volatile("s_waitcnt vmcnt(2)" ::: "memory")

    STAGE(0, 0, 0, 0); STAGE(0, 0, 1, 0); STAGE(0, 1, 0, 0); STAGE(0, 1, 1, 0);
    STAGE(1, 1, 0, 1);
    VMC2; BARX;

#pragma unroll 1
    for (int i = 0; i < 8; ++i) {
        const int t = 2 * i;
        const bool pre = (i < 7);
        RDA(0, 0, 0); RDB(0, 0); STAGE(1, 1, 1, t + 1);
        BARX; LGK0; MM(0); BARX;
        RDA(0, 1, 0); STAGE(1, 0, 0, t + 1);
        BARX; LGK0; MM(1); BARX;
        RDA(0, 0, 1); RDB(0, 1); STAGE(1, 0, 1, t + 1);
        BARX; LGK0; MM(0); BARX;
        RDA(0, 1, 1); if (pre) STAGE(0, 1, 0, t + 2);
        BARX; LGK0; MM(1); VMC2; BARX;
        RDA(1, 0, 0); RDB(1, 0); if (pre) STAGE(0, 1, 1, t + 2);
        BARX; LGK0; MM(0); BARX;
        RDA(1, 1, 0); if (pre) STAGE(0, 0, 0, t + 2);
        BARX; LGK0; MM(1); BARX;
        RDA(1, 0, 1); RDB(1, 1); if (pre) STAGE(0, 0, 1, t + 2);
        BARX; LGK0; MM(0); BARX;
        RDA(1, 1, 1); if (pre) STAGE(1, 1, 0, t + 3);
        BARX; LGK0; MM(1); VMC2; BARX;
    }
#undef BARX
#undef LGK0
#undef VMC2

    const float* biasg = jb.bias + (size_t)(jb.routed ? (rt[m0 >> 10]) : 0) * NE;
#pragma unroll
    for (int am = 0; am < 8; ++am) {
        int row = m0 + wm * 128 + am * 16 + g4 * 4;
#pragma unroll
        for (int nf = 0; nf < 4; ++nf) {
            int col = n0 + wn * 64 + nf * 16 + frow;
            float bv = biasg[col];
            f32x4 v = acc[am][nf];
#pragma unroll
            for (int r = 0; r < 4; ++r) {
                float val = (v[r] + bv) * jb.scale;
                if (OUT_F32)
                    ((float*)jb.out)[(size_t)(row + r) * NE + col] = val;
                else
                    ((unsigned short*)jb.out)[(size_t)(row + r) * NE + col] = f2bf(val);
            }
        }
    }
}

// ---------------- V transpose: Vt[(b,h),d,s] = V[b,s,h*64+d] ----------------
__global__ void k_vtrans(const unsigned short* __restrict__ V, unsigned short* __restrict__ Vt) {
    __shared__ unsigned short tile[64][65];
    const int blk = blockIdx.x;
    const int bh = blk >> 4;
    const int b = bh >> 4;
    const int h = bh & 15;
    const int s0 = (blk & 15) * 64;
    const int tid = threadIdx.x;
#pragma unroll
    for (int i = 0; i < 2; ++i) {
        int seg = tid + i * 256;
        int row = seg >> 3;
        int c8 = (seg & 7) * 8;
        const unsigned short* src = V + (size_t)(b * NT + s0 + row) * NE + h * 64 + c8;
        ushort4 u0 = *reinterpret_cast<const ushort4*>(src);
        ushort4 u1 = *reinterpret_cast<const ushort4*>(src + 4);
        tile[row][c8 + 0] = u0.x; tile[row][c8 + 1] = u0.y;
        tile[row][c8 + 2] = u0.z; tile[row][c8 + 3] = u0.w;
        tile[row][c8 + 4] = u1.x; tile[row][c8 + 5] = u1.y;
        tile[row][c8 + 6] = u1.z; tile[row][c8 + 7] = u1.w;
    }
    __syncthreads();
#pragma unroll
    for (int i = 0; i < 2; ++i) {
        int seg = tid + i * 256;
        int drow = seg >> 3;
        int s8 = (seg & 7) * 8;
        ushort4 u0, u1;
        u0.x = tile[s8 + 0][drow]; u0.y = tile[s8 + 1][drow];
        u0.z = tile[s8 + 2][drow]; u0.w = tile[s8 + 3][drow];
        u1.x = tile[s8 + 4][drow]; u1.y = tile[s8 + 5][drow];
        u1.z = tile[s8 + 6][drow]; u1.w = tile[s8 + 7][drow];
        unsigned short* dst = Vt + (size_t)(bh * 64 + drow) * NT + s0 + s8;
        *reinterpret_cast<ushort4*>(dst) = u0;
        *reinterpret_cast<ushort4*>(dst + 4) = u1;
    }
}

// ---------------- fused dual-stream attention, swapped-QK^T ------------------
// 8 waves x 16 q-rows; KVBLK=64; LDS-staged K/Kr/V (dbuf, chunk-XOR swizzle).
// V-frags shared across streams; dual P buffers with s-half split (PLD=40)
// -> 28KB LDS read / wave-iter (was 36KB). No-max exp accumulation.
__global__ __launch_bounds__(512, 4)
void k_attn(const unsigned short* __restrict__ Q,
            const unsigned short* __restrict__ K,
            const unsigned short* __restrict__ Qr,
            const unsigned short* __restrict__ Kr,
            const unsigned short* __restrict__ Vt,
            unsigned short* __restrict__ attnO)
{
    constexpr int PLD = 40;   // 80B rows (16B-aligned); half-tile = 16 rows x 32 s
    __shared__ __attribute__((aligned(16))) unsigned short KV[2][3 * 4096];   // Kg|Kr|V 8KB each
    __shared__ __attribute__((aligned(16))) unsigned short Pga[8][16 * PLD];  // per-wave Pg half
    __shared__ __attribute__((aligned(16))) unsigned short Pra[8][16 * PLD];  // per-wave Pr half

    // bijective XCD swizzle: all 8 blocks of one head on one XCD
    const int blk = (blockIdx.x & 7) * 128 + (blockIdx.x >> 3);
    const int tile = blk & 7;
    const int bh = blk >> 3;
    const int b = bh >> 4;
    const int h = bh & 15;
    const int wid = threadIdx.x >> 6;
    const int lane = threadIdx.x & 63;
    const int frow = lane & 15;
    const int g4 = lane >> 4;
    const int f7 = frow & 7;
    const int fk8 = g4 * 8;
    const int t0 = tile * 128 + wid * 16;

    const size_t qoff = (size_t)(b * NT + t0 + frow) * NE + h * 64;
    const bf16x8 qf0 = *reinterpret_cast<const bf16x8*>(Q + qoff + fk8);
    const bf16x8 qf1 = *reinterpret_cast<const bf16x8*>(Q + qoff + 32 + fk8);
    const bf16x8 qr0 = *reinterpret_cast<const bf16x8*>(Qr + qoff + fk8);
    const bf16x8 qr1 = *reinterpret_cast<const bf16x8*>(Qr + qoff + 32 + fk8);

    const unsigned short* Kb  = K  + (size_t)b * NT * NE + h * 64;
    const unsigned short* Krb = Kr + (size_t)b * NT * NE + h * 64;
    const unsigned short* Vtb = Vt + (size_t)bh * 64 * NT;
    unsigned short* PgRow = &Pga[wid][0] + frow * PLD;
    unsigned short* PrRow = &Pra[wid][0] + frow * PLD;

    f32x4 og[4], orr[4];
    float lgp = 0.f, lrp = 0.f;
#pragma unroll
    for (int i = 0; i < 4; ++i) {
        og[i] = (f32x4){0.f, 0.f, 0.f, 0.f};
        orr[i] = (f32x4){0.f, 0.f, 0.f, 0.f};
    }

    // staging: 64 rows x 8 chunks per 8KB section; chunk (row,c) holds
    // src[row][8*(c ^ (row&7)) ..+8]; LDS dest linear (wave-uniform + lane*16)
    const int srow = threadIdx.x >> 3;                         // 0..63
    const int scb8 = ((threadIdx.x & 7) ^ (srow & 7)) * 8;
    auto stage = [&](int buf, int s0) {
        const unsigned short* sK = Kb  + (size_t)(s0 + srow) * NE + scb8;
        const unsigned short* sR = Krb + (size_t)(s0 + srow) * NE + scb8;
        const unsigned short* sV = Vtb + (size_t)srow * NT + s0 + scb8;
        __builtin_amdgcn_global_load_lds((AS1 void*)sK, (AS3 void*)(&KV[buf][wid * 512]), 16, 0, 0);
        __builtin_amdgcn_global_load_lds((AS1 void*)sR, (AS3 void*)(&KV[buf][4096 + wid * 512]), 16, 0, 0);
        __builtin_amdgcn_global_load_lds((AS1 void*)sV, (AS3 void*)(&KV[buf][8192 + wid * 512]), 16, 0, 0);
    };

    stage(0, 0);
    __syncthreads();
    int cur = 0;
    const f32x4 z = (f32x4){0.f, 0.f, 0.f, 0.f};
#pragma unroll 1
    for (int t = 0; t < NT / 64; ++t) {
        if (t < NT / 64 - 1) stage(cur ^ 1, (t + 1) * 64);
        const unsigned short* Kl  = &KV[cur][0];
        const unsigned short* Krl = &KV[cur][4096];
        const unsigned short* Vl  = &KV[cur][8192];

        // QK^T swapped: sg[nf] lane = S[q=frow][s=16nf+4g4+r]
        f32x4 sg[4], sr[4];
#pragma unroll
        for (int nf = 0; nf < 4; ++nf) {
            const int ro = (nf * 16 + frow) * 64;
            bf16x8 kA = *reinterpret_cast<const bf16x8*>(Kl + ro + ((g4 ^ f7) * 8));
            bf16x8 kB = *reinterpret_cast<const bf16x8*>(Kl + ro + (((4 + g4) ^ f7) * 8));
            bf16x8 rA = *reinterpret_cast<const bf16x8*>(Krl + ro + ((g4 ^ f7) * 8));
            bf16x8 rB = *reinterpret_cast<const bf16x8*>(Krl + ro + (((4 + g4) ^ f7) * 8));
            sg[nf] = __builtin_amdgcn_mfma_f32_16x16x32_bf16(kA, qf0, z, 0, 0, 0);
            sg[nf] = __builtin_amdgcn_mfma_f32_16x16x32_bf16(kB, qf1, sg[nf], 0, 0, 0);
            sr[nf] = __builtin_amdgcn_mfma_f32_16x16x32_bf16(rA, qr0, z, 0, 0, 0);
            sr[nf] = __builtin_amdgcn_mfma_f32_16x16x32_bf16(rB, qr1, sr[nf], 0, 0, 0);
        }

        // two s-halves: pack both streams, one wait, PV with shared V-frags
#pragma unroll
        for (int hh = 0; hh < 2; ++hh) {
#pragma unroll
            for (int j = 0; j < 2; ++j) {
                const int nf = 2 * hh + j;
                float g0 = __expf(sg[nf][0]), g1 = __expf(sg[nf][1]);
                float g2 = __expf(sg[nf][2]), g3 = __expf(sg[nf][3]);
                lgp += (g0 + g1) + (g2 + g3);
                uint2 wg;
                wg.x = cvt_pk_bf16(g0, g1);
                wg.y = cvt_pk_bf16(g2, g3);
                *reinterpret_cast<uint2*>(PgRow + j * 16 + g4 * 4) = wg;
                float r0 = __expf(sr[nf][0]), r1 = __expf(sr[nf][1]);
                float r2 = __expf(sr[nf][2]), r3 = __expf(sr[nf][3]);
                lrp += (r0 + r1) + (r2 + r3);
                uint2 wr;
                wr.x = cvt_pk_bf16(r0, r1);
                wr.y = cvt_pk_bf16(r2, r3);
                *reinterpret_cast<uint2*>(PrRow + j * 16 + g4 * 4) = wr;
            }
            asm volatile("s_waitcnt lgkmcnt(0)" ::: "memory");   // P visible (same wave)
            bf16x8 pg = *reinterpret_cast<const bf16x8*>(PgRow + fk8);
            bf16x8 pr = *reinterpret_cast<const bf16x8*>(PrRow + fk8);
            __builtin_amdgcn_s_setprio(1);
#pragma unroll
            for (int nf2 = 0; nf2 < 4; ++nf2) {
                const int vo = (nf2 * 16 + frow) * 64;
                bf16x8 v = *reinterpret_cast<const bf16x8*>(Vl + vo + (((4 * hh + g4) ^ f7) * 8));
                og[nf2]  = __builtin_amdgcn_mfma_f32_16x16x32_bf16(pg, v, og[nf2], 0, 0, 0);
                orr[nf2] = __builtin_amdgcn_mfma_f32_16x16x32_bf16(pr, v, orr[nf2], 0, 0, 0);
            }
            __builtin_amdgcn_s_setprio(0);
        }

        __syncthreads();   // drains vmcnt (next KV tile staged) + overwrite fence
        cur ^= 1;
    }

    // full row sums for q-row frow (reduce across the 4 g4 lanes)
    lgp += __shfl_xor(lgp, 16); lgp += __shfl_xor(lgp, 32);
    lrp += __shfl_xor(lrp, 16); lrp += __shfl_xor(lrp, 32);
    float ig = 0.45f / lgp, ir = 0.05f / lrp;
    // redistribute: output lane owns q-rows 4*g4+r; scales live at lane 4*g4+r
    float igr[4], irr[4];
#pragma unroll
    for (int r = 0; r < 4; ++r) {
        igr[r] = __shfl(ig, g4 * 4 + r);
        irr[r] = __shfl(ir, g4 * 4 + r);
    }
#pragma unroll
    for (int nf2 = 0; nf2 < 4; ++nf2) {
#pragma unroll
        for (int r = 0; r < 4; ++r) {
            float val = og[nf2][r] * igr[r] + orr[nf2][r] * irr[r];
            int tq = t0 + g4 * 4 + r;
            attnO[(size_t)(b * NT + tq) * NE + h * 64 + nf2 * 16 + frow] = f2bf(val);
        }
    }
}

// ---------------- launcher ----------------
extern "C" void kernel_launch(void* const* d_in, const int* in_sizes, int n_in,
                              void* d_out, int out_size, void* d_ws, size_t ws_size,
                              hipStream_t stream)
{
    const float* hs  = (const float*)d_in[0];
    const int*   rt  = (const int*)d_in[1];
    const float* Wq  = (const float*)d_in[2];
    const float* bq  = (const float*)d_in[3];
    const float* Wk  = (const float*)d_in[4];
    const float* bk  = (const float*)d_in[5];
    const float* Wv  = (const float*)d_in[6];
    const float* bv  = (const float*)d_in[7];
    const float* Wo  = (const float*)d_in[8];
    const float* bo  = (const float*)d_in[9];
    const float* RWq = (const float*)d_in[10];
    const float* Rbq = (const float*)d_in[11];
    const float* RWk = (const float*)d_in[12];
    const float* Rbk = (const float*)d_in[13];

    unsigned short* w = (unsigned short*)d_ws;
    const size_t NBT = (size_t)BT * NE;   // 8M elems
    const size_t NW  = (size_t)NE * NE;   // 1M elems
    unsigned short* hsB  = w; w += NBT;
    unsigned short* Qb   = w; w += NBT;
    unsigned short* Kb   = w; w += NBT;
    unsigned short* Vb   = w; w += NBT;
    unsigned short* Qrb  = w; w += NBT;
    unsigned short* Krb  = w; w += NBT;
    unsigned short* Vtb  = w; w += NBT;
    unsigned short* atb  = w; w += NBT;
    unsigned short* WqB  = w; w += NW;
    unsigned short* WkB  = w; w += NW;
    unsigned short* WvB  = w; w += NW;
    unsigned short* WoB  = w; w += NW;
    unsigned short* RWqB = w; w += 4 * NW;
    unsigned short* RWkB = w; w += 4 * NW;

    k_cvt7<<<dim3(20480), dim3(256), 0, stream>>>(hs, hsB, Wq, WqB, Wk, WkB, Wv, WvB,
                                                  Wo, WoB, RWq, RWqB, RWk, RWkB);

    GJob jq  = { WqB,  bq,  Qb,  0.125f, 0 };
    GJob jk  = { WkB,  bk,  Kb,  1.0f,   0 };
    GJob jv  = { WvB,  bv,  Vb,  1.0f,   0 };
    GJob jrq = { RWqB, Rbq, Qrb, 0.125f, 1 };
    GJob jrk = { RWkB, Rbk, Krb, 1.0f,   1 };
    k_gemm256<false><<<dim3(640), dim3(512), 0, stream>>>(hsB, jq, jk, jv, jrq, jrk, rt, 80);

    k_vtrans<<<dim3(NB * NH * 16), dim3(256), 0, stream>>>(Vb, Vtb);
    k_attn<<<dim3(NB * NH * 8), dim3(512), 0, stream>>>(Qb, Kb, Qrb, Krb, Vtb, atb);

    GJob jo = { WoB, bo, d_out, 1.0f, 0 };
    k_gemm256<true><<<dim3(128), dim3(512), 0, stream>>>(atb, jo, jo, jo, jo, jo, nullptr, 16);
}

// Round 8
// 240.180 us; speedup vs baseline: 2.3393x; 1.0065x over previous
//
#include <hip/hip_runtime.h>
#include <stdint.h>

#define AS1 __attribute__((address_space(1)))
#define AS3 __attribute__((address_space(3)))

typedef __attribute__((ext_vector_type(8))) short bf16x8;   // 8 bf16 = 4 VGPRs
typedef __attribute__((ext_vector_type(4))) float f32x4;

#define NB 8
#define NT 1024
#define NE 1024
#define NH 16
#define BT (NB * NT)

__device__ __forceinline__ unsigned short f2bf(float f) {
    unsigned int u = __builtin_bit_cast(unsigned int, f);
    u += 0x7FFFu + ((u >> 16) & 1u);          // RNE
    return (unsigned short)(u >> 16);
}
// pack two f32 -> one u32 of 2 bf16 (RNE) in a single VALU op
__device__ __forceinline__ unsigned int cvt_pk_bf16(float lo, float hi) {
    unsigned int r;
    asm("v_cvt_pk_bf16_f32 %0, %1, %2" : "=v"(r) : "v"(lo), "v"(hi));
    return r;
}

// ---------------- fused f32 -> bf16 conversion, 7 segments ----------------
__global__ void k_cvt7(const float* __restrict__ hs, unsigned short* __restrict__ hsB,
                       const float* __restrict__ w1, unsigned short* __restrict__ w1B,
                       const float* __restrict__ w2, unsigned short* __restrict__ w2B,
                       const float* __restrict__ w3, unsigned short* __restrict__ w3B,
                       const float* __restrict__ w4, unsigned short* __restrict__ w4B,
                       const float* __restrict__ r1, unsigned short* __restrict__ r1B,
                       const float* __restrict__ r2, unsigned short* __restrict__ r2B)
{
    int blk = blockIdx.x;
    const float* s; unsigned short* d; int base;
    if      (blk < 8192)  { s = hs; d = hsB; base = 0; }
    else if (blk < 9216)  { s = w1; d = w1B; base = 8192; }
    else if (blk < 10240) { s = w2; d = w2B; base = 9216; }
    else if (blk < 11264) { s = w3; d = w3B; base = 10240; }
    else if (blk < 12288) { s = w4; d = w4B; base = 11264; }
    else if (blk < 16384) { s = r1; d = r1B; base = 12288; }
    else                  { s = r2; d = r2B; base = 16384; }
    int i = ((blk - base) * 256 + threadIdx.x) * 4;
    float4 f = *reinterpret_cast<const float4*>(s + i);
    ushort4 o;
    o.x = f2bf(f.x); o.y = f2bf(f.y); o.z = f2bf(f.z); o.w = f2bf(f.w);
    *reinterpret_cast<ushort4*>(d + i) = o;
}

// ============ 256x256 8-phase GEMM (T2+T3+T4+T5), C = A·W^T + bias =========
// L2-aware block mapping: each XCD owns by = xcd*4..xcd*4+3 for ALL jobs
// (inner order pz,byl,bx) -> per-pz working set 4MB (4 A + 4 B panels) fits
// one XCD L2; A panels (shared hsB) reused 20x within the XCD.
struct GJob {
    const unsigned short* W;
    const float* bias;
    void* out;
    float scale;
    int routed;
};

template <bool OUT_F32>
__global__ __launch_bounds__(512, 2)
void k_gemm256(const unsigned short* __restrict__ A,
               GJob j0, GJob j1, GJob j2, GJob j3, GJob j4,
               const int* __restrict__ rt)
{
    __shared__ __attribute__((aligned(16))) unsigned short LB[2][2][2][128 * 64];

    const int flat = blockIdx.x;
    const int xcd = flat & 7;           // consecutive blocks round-robin XCDs
    const int l   = flat >> 3;          // sequence within this XCD
    const int pz  = l >> 4;             // job
    const int r   = l & 15;
    const int by  = xcd * 4 + (r >> 2); // 4 m-panels per XCD, all jobs
    const int bx  = r & 3;
    const int m0 = by << 8, n0 = bx << 8;

    GJob jb = j0;
    if (pz == 1) jb = j1;
    else if (pz == 2) jb = j2;
    else if (pz == 3) jb = j3;
    else if (pz == 4) jb = j4;
    int g = jb.routed ? rt[m0 >> 10] : 0;
    const unsigned short* Wg = jb.W + (size_t)g * NE * NE;

    const int tid  = threadIdx.x;
    const int wid  = tid >> 6;
    const int lane = tid & 63;
    const int frow = lane & 15;
    const int g4   = lane >> 4;
    const int wm = wid >> 2, wn = wid & 3;

    const int rh0  = tid >> 3;
    const int swz8 = ((tid & 7) ^ (rh0 & 7)) * 8;
    const unsigned short* baseA = A  + (size_t)m0 * NE;
    const unsigned short* baseB = Wg + (size_t)n0 * NE;

    auto STAGE = [&](int d, int mat, int half, int kt) {
        const unsigned short* base = mat ? baseB : baseA;
#pragma unroll
        for (int j = 0; j < 2; ++j) {
            const unsigned short* src =
                base + (size_t)(half * 128 + rh0 + j * 64) * NE + kt * 64 + swz8;
            __builtin_amdgcn_global_load_lds((AS1 void*)src,
                (AS3 void*)&LB[d][mat][half][(wid * 64 + j * 512) * 8], 16, 0, 0);
        }
    };

    f32x4 acc[8][4];
#pragma unroll
    for (int m = 0; m < 8; ++m)
#pragma unroll
        for (int n = 0; n < 4; ++n) acc[m][n] = (f32x4){0.f, 0.f, 0.f, 0.f};

    bf16x8 a4[4], b4[4];
    auto RDA = [&](int d, int mh, int kh) {
#pragma unroll
        for (int mf = 0; mf < 4; ++mf) {
            int rh = mh * 64 + mf * 16 + frow;
            int off = rh * 64 + (((kh * 4 + g4) ^ (frow & 7)) * 8);
            a4[mf] = *reinterpret_cast<const bf16x8*>(&LB[d][0][wm][off]);
        }
    };
    auto RDB = [&](int d, int kh) {
#pragma unroll
        for (int nf = 0; nf < 4; ++nf) {
            int rh = (wn & 1) * 64 + nf * 16 + frow;
            int off = rh * 64 + (((kh * 4 + g4) ^ (frow & 7)) * 8);
            b4[nf] = *reinterpret_cast<const bf16x8*>(&LB[d][1][wn >> 1][off]);
        }
    };
    auto MM = [&](int mh) {
        __builtin_amdgcn_s_setprio(1);
#pragma unroll
        for (int mf = 0; mf < 4; ++mf)
#pragma unroll
            for (int nf = 0; nf < 4; ++nf)
                acc[mh * 4 + mf][nf] =
                    __builtin_amdgcn_mfma_f32_16x16x32_bf16(a4[mf], b4[nf], acc[mh * 4 + mf][nf], 0, 0, 0);
        __builtin_amdgcn_s_setprio(0);
    };

#define BARX __builtin_amdgcn_s_barrier()
#define LGK0 asm volatile("s_waitcnt lgkmcnt(0)" ::: "memory")
#define VMC2 asm volatile("s_waitcnt vmcnt(2)" ::: "memory")

    STAGE(0, 0, 0, 0); STAGE(0, 0, 1, 0); STAGE(0, 1, 0, 0); STAGE(0, 1, 1, 0);
    STAGE(1, 1, 0, 1);
    VMC2; BARX;

#pragma unroll 1
    for (int i = 0; i < 8; ++i) {
        const int t = 2 * i;
        const bool pre = (i < 7);
        RDA(0, 0, 0); RDB(0, 0); STAGE(1, 1, 1, t + 1);
        BARX; LGK0; MM(0); BARX;
        RDA(0, 1, 0); STAGE(1, 0, 0, t + 1);
        BARX; LGK0; MM(1); BARX;
        RDA(0, 0, 1); RDB(0, 1); STAGE(1, 0, 1, t + 1);
        BARX; LGK0; MM(0); BARX;
        RDA(0, 1, 1); if (pre) STAGE(0, 1, 0, t + 2);
        BARX; LGK0; MM(1); VMC2; BARX;
        RDA(1, 0, 0); RDB(1, 0); if (pre) STAGE(0, 1, 1, t + 2);
        BARX; LGK0; MM(0); BARX;
        RDA(1, 1, 0); if (pre) STAGE(0, 0, 0, t + 2);
        BARX; LGK0; MM(1); BARX;
        RDA(1, 0, 1); RDB(1, 1); if (pre) STAGE(0, 0, 1, t + 2);
        BARX; LGK0; MM(0); BARX;
        RDA(1, 1, 1); if (pre) STAGE(1, 1, 0, t + 3);
        BARX; LGK0; MM(1); VMC2; BARX;
    }
#undef BARX
#undef LGK0
#undef VMC2

    const float* biasg = jb.bias + (size_t)(jb.routed ? (rt[m0 >> 10]) : 0) * NE;
#pragma unroll
    for (int am = 0; am < 8; ++am) {
        int row = m0 + wm * 128 + am * 16 + g4 * 4;
#pragma unroll
        for (int nf = 0; nf < 4; ++nf) {
            int col = n0 + wn * 64 + nf * 16 + frow;
            float bv = biasg[col];
            f32x4 v = acc[am][nf];
#pragma unroll
            for (int r2 = 0; r2 < 4; ++r2) {
                float val = (v[r2] + bv) * jb.scale;
                if (OUT_F32)
                    ((float*)jb.out)[(size_t)(row + r2) * NE + col] = val;
                else
                    ((unsigned short*)jb.out)[(size_t)(row + r2) * NE + col] = f2bf(val);
            }
        }
    }
}

// ---------------- V transpose: Vt[(b,h),d,s] = V[b,s,h*64+d] ----------------
__global__ void k_vtrans(const unsigned short* __restrict__ V, unsigned short* __restrict__ Vt) {
    __shared__ unsigned short tile[64][65];
    const int blk = blockIdx.x;
    const int bh = blk >> 4;
    const int b = bh >> 4;
    const int h = bh & 15;
    const int s0 = (blk & 15) * 64;
    const int tid = threadIdx.x;
#pragma unroll
    for (int i = 0; i < 2; ++i) {
        int seg = tid + i * 256;
        int row = seg >> 3;
        int c8 = (seg & 7) * 8;
        const unsigned short* src = V + (size_t)(b * NT + s0 + row) * NE + h * 64 + c8;
        ushort4 u0 = *reinterpret_cast<const ushort4*>(src);
        ushort4 u1 = *reinterpret_cast<const ushort4*>(src + 4);
        tile[row][c8 + 0] = u0.x; tile[row][c8 + 1] = u0.y;
        tile[row][c8 + 2] = u0.z; tile[row][c8 + 3] = u0.w;
        tile[row][c8 + 4] = u1.x; tile[row][c8 + 5] = u1.y;
        tile[row][c8 + 6] = u1.z; tile[row][c8 + 7] = u1.w;
    }
    __syncthreads();
#pragma unroll
    for (int i = 0; i < 2; ++i) {
        int seg = tid + i * 256;
        int drow = seg >> 3;
        int s8 = (seg & 7) * 8;
        ushort4 u0, u1;
        u0.x = tile[s8 + 0][drow]; u0.y = tile[s8 + 1][drow];
        u0.z = tile[s8 + 2][drow]; u0.w = tile[s8 + 3][drow];
        u1.x = tile[s8 + 4][drow]; u1.y = tile[s8 + 5][drow];
        u1.z = tile[s8 + 6][drow]; u1.w = tile[s8 + 7][drow];
        unsigned short* dst = Vt + (size_t)(bh * 64 + drow) * NT + s0 + s8;
        *reinterpret_cast<ushort4*>(dst) = u0;
        *reinterpret_cast<ushort4*>(dst + 4) = u1;
    }
}

// ---------------- fused dual-stream attention, swapped-QK^T ------------------
// (unchanged from R7)
__global__ __launch_bounds__(512, 4)
void k_attn(const unsigned short* __restrict__ Q,
            const unsigned short* __restrict__ K,
            const unsigned short* __restrict__ Qr,
            const unsigned short* __restrict__ Kr,
            const unsigned short* __restrict__ Vt,
            unsigned short* __restrict__ attnO)
{
    constexpr int PLD = 40;   // 80B rows (16B-aligned); half-tile = 16 rows x 32 s
    __shared__ __attribute__((aligned(16))) unsigned short KV[2][3 * 4096];   // Kg|Kr|V 8KB each
    __shared__ __attribute__((aligned(16))) unsigned short Pga[8][16 * PLD];  // per-wave Pg half
    __shared__ __attribute__((aligned(16))) unsigned short Pra[8][16 * PLD];  // per-wave Pr half

    const int blk = (blockIdx.x & 7) * 128 + (blockIdx.x >> 3);
    const int tile = blk & 7;
    const int bh = blk >> 3;
    const int b = bh >> 4;
    const int h = bh & 15;
    const int wid = threadIdx.x >> 6;
    const int lane = threadIdx.x & 63;
    const int frow = lane & 15;
    const int g4 = lane >> 4;
    const int f7 = frow & 7;
    const int fk8 = g4 * 8;
    const int t0 = tile * 128 + wid * 16;

    const size_t qoff = (size_t)(b * NT + t0 + frow) * NE + h * 64;
    const bf16x8 qf0 = *reinterpret_cast<const bf16x8*>(Q + qoff + fk8);
    const bf16x8 qf1 = *reinterpret_cast<const bf16x8*>(Q + qoff + 32 + fk8);
    const bf16x8 qr0 = *reinterpret_cast<const bf16x8*>(Qr + qoff + fk8);
    const bf16x8 qr1 = *reinterpret_cast<const bf16x8*>(Qr + qoff + 32 + fk8);

    const unsigned short* Kb  = K  + (size_t)b * NT * NE + h * 64;
    const unsigned short* Krb = Kr + (size_t)b * NT * NE + h * 64;
    const unsigned short* Vtb = Vt + (size_t)bh * 64 * NT;
    unsigned short* PgRow = &Pga[wid][0] + frow * PLD;
    unsigned short* PrRow = &Pra[wid][0] + frow * PLD;

    f32x4 og[4], orr[4];
    float lgp = 0.f, lrp = 0.f;
#pragma unroll
    for (int i = 0; i < 4; ++i) {
        og[i] = (f32x4){0.f, 0.f, 0.f, 0.f};
        orr[i] = (f32x4){0.f, 0.f, 0.f, 0.f};
    }

    const int srow = threadIdx.x >> 3;                         // 0..63
    const int scb8 = ((threadIdx.x & 7) ^ (srow & 7)) * 8;
    auto stage = [&](int buf, int s0) {
        const unsigned short* sK = Kb  + (size_t)(s0 + srow) * NE + scb8;
        const unsigned short* sR = Krb + (size_t)(s0 + srow) * NE + scb8;
        const unsigned short* sV = Vtb + (size_t)srow * NT + s0 + scb8;
        __builtin_amdgcn_global_load_lds((AS1 void*)sK, (AS3 void*)(&KV[buf][wid * 512]), 16, 0, 0);
        __builtin_amdgcn_global_load_lds((AS1 void*)sR, (AS3 void*)(&KV[buf][4096 + wid * 512]), 16, 0, 0);
        __builtin_amdgcn_global_load_lds((AS1 void*)sV, (AS3 void*)(&KV[buf][8192 + wid * 512]), 16, 0, 0);
    };

    stage(0, 0);
    __syncthreads();
    int cur = 0;
    const f32x4 z = (f32x4){0.f, 0.f, 0.f, 0.f};
#pragma unroll 1
    for (int t = 0; t < NT / 64; ++t) {
        if (t < NT / 64 - 1) stage(cur ^ 1, (t + 1) * 64);
        const unsigned short* Kl  = &KV[cur][0];
        const unsigned short* Krl = &KV[cur][4096];
        const unsigned short* Vl  = &KV[cur][8192];

        // QK^T swapped: sg[nf] lane = S[q=frow][s=16nf+4g4+r]
        f32x4 sg[4], sr[4];
#pragma unroll
        for (int nf = 0; nf < 4; ++nf) {
            const int ro = (nf * 16 + frow) * 64;
            bf16x8 kA = *reinterpret_cast<const bf16x8*>(Kl + ro + ((g4 ^ f7) * 8));
            bf16x8 kB = *reinterpret_cast<const bf16x8*>(Kl + ro + (((4 + g4) ^ f7) * 8));
            bf16x8 rA = *reinterpret_cast<const bf16x8*>(Krl + ro + ((g4 ^ f7) * 8));
            bf16x8 rB = *reinterpret_cast<const bf16x8*>(Krl + ro + (((4 + g4) ^ f7) * 8));
            sg[nf] = __builtin_amdgcn_mfma_f32_16x16x32_bf16(kA, qf0, z, 0, 0, 0);
            sg[nf] = __builtin_amdgcn_mfma_f32_16x16x32_bf16(kB, qf1, sg[nf], 0, 0, 0);
            sr[nf] = __builtin_amdgcn_mfma_f32_16x16x32_bf16(rA, qr0, z, 0, 0, 0);
            sr[nf] = __builtin_amdgcn_mfma_f32_16x16x32_bf16(rB, qr1, sr[nf], 0, 0, 0);
        }

        // two s-halves: pack both streams, one wait, PV with shared V-frags
#pragma unroll
        for (int hh = 0; hh < 2; ++hh) {
#pragma unroll
            for (int j = 0; j < 2; ++j) {
                const int nf = 2 * hh + j;
                float g0 = __expf(sg[nf][0]), g1 = __expf(sg[nf][1]);
                float g2 = __expf(sg[nf][2]), g3 = __expf(sg[nf][3]);
                lgp += (g0 + g1) + (g2 + g3);
                uint2 wg;
                wg.x = cvt_pk_bf16(g0, g1);
                wg.y = cvt_pk_bf16(g2, g3);
                *reinterpret_cast<uint2*>(PgRow + j * 16 + g4 * 4) = wg;
                float r0 = __expf(sr[nf][0]), r1 = __expf(sr[nf][1]);
                float r2 = __expf(sr[nf][2]), r3 = __expf(sr[nf][3]);
                lrp += (r0 + r1) + (r2 + r3);
                uint2 wr;
                wr.x = cvt_pk_bf16(r0, r1);
                wr.y = cvt_pk_bf16(r2, r3);
                *reinterpret_cast<uint2*>(PrRow + j * 16 + g4 * 4) = wr;
            }
            asm volatile("s_waitcnt lgkmcnt(0)" ::: "memory");   // P visible (same wave)
            bf16x8 pg = *reinterpret_cast<const bf16x8*>(PgRow + fk8);
            bf16x8 pr = *reinterpret_cast<const bf16x8*>(PrRow + fk8);
            __builtin_amdgcn_s_setprio(1);
#pragma unroll
            for (int nf2 = 0; nf2 < 4; ++nf2) {
                const int vo = (nf2 * 16 + frow) * 64;
                bf16x8 v = *reinterpret_cast<const bf16x8*>(Vl + vo + (((4 * hh + g4) ^ f7) * 8));
                og[nf2]  = __builtin_amdgcn_mfma_f32_16x16x32_bf16(pg, v, og[nf2], 0, 0, 0);
                orr[nf2] = __builtin_amdgcn_mfma_f32_16x16x32_bf16(pr, v, orr[nf2], 0, 0, 0);
            }
            __builtin_amdgcn_s_setprio(0);
        }

        __syncthreads();   // drains vmcnt (next KV tile staged) + overwrite fence
        cur ^= 1;
    }

    // full row sums for q-row frow (reduce across the 4 g4 lanes)
    lgp += __shfl_xor(lgp, 16); lgp += __shfl_xor(lgp, 32);
    lrp += __shfl_xor(lrp, 16); lrp += __shfl_xor(lrp, 32);
    float ig = 0.45f / lgp, ir = 0.05f / lrp;
    float igr[4], irr[4];
#pragma unroll
    for (int r = 0; r < 4; ++r) {
        igr[r] = __shfl(ig, g4 * 4 + r);
        irr[r] = __shfl(ir, g4 * 4 + r);
    }
#pragma unroll
    for (int nf2 = 0; nf2 < 4; ++nf2) {
#pragma unroll
        for (int r = 0; r < 4; ++r) {
            float val = og[nf2][r] * igr[r] + orr[nf2][r] * irr[r];
            int tq = t0 + g4 * 4 + r;
            attnO[(size_t)(b * NT + tq) * NE + h * 64 + nf2 * 16 + frow] = f2bf(val);
        }
    }
}

// ---------------- launcher ----------------
extern "C" void kernel_launch(void* const* d_in, const int* in_sizes, int n_in,
                              void* d_out, int out_size, void* d_ws, size_t ws_size,
                              hipStream_t stream)
{
    const float* hs  = (const float*)d_in[0];
    const int*   rt  = (const int*)d_in[1];
    const float* Wq  = (const float*)d_in[2];
    const float* bq  = (const float*)d_in[3];
    const float* Wk  = (const float*)d_in[4];
    const float* bk  = (const float*)d_in[5];
    const float* Wv  = (const float*)d_in[6];
    const float* bv  = (const float*)d_in[7];
    const float* Wo  = (const float*)d_in[8];
    const float* bo  = (const float*)d_in[9];
    const float* RWq = (const float*)d_in[10];
    const float* Rbq = (const float*)d_in[11];
    const float* RWk = (const float*)d_in[12];
    const float* Rbk = (const float*)d_in[13];

    unsigned short* w = (unsigned short*)d_ws;
    const size_t NBT = (size_t)BT * NE;   // 8M elems
    const size_t NW  = (size_t)NE * NE;   // 1M elems
    unsigned short* hsB  = w; w += NBT;
    unsigned short* Qb   = w; w += NBT;
    unsigned short* Kb   = w; w += NBT;
    unsigned short* Vb   = w; w += NBT;
    unsigned short* Qrb  = w; w += NBT;
    unsigned short* Krb  = w; w += NBT;
    unsigned short* Vtb  = w; w += NBT;
    unsigned short* atb  = w; w += NBT;
    unsigned short* WqB  = w; w += NW;
    unsigned short* WkB  = w; w += NW;
    unsigned short* WvB  = w; w += NW;
    unsigned short* WoB  = w; w += NW;
    unsigned short* RWqB = w; w += 4 * NW;
    unsigned short* RWkB = w; w += 4 * NW;

    k_cvt7<<<dim3(20480), dim3(256), 0, stream>>>(hs, hsB, Wq, WqB, Wk, WkB, Wv, WvB,
                                                  Wo, WoB, RWq, RWqB, RWk, RWkB);

    GJob jq  = { WqB,  bq,  Qb,  0.125f, 0 };
    GJob jk  = { WkB,  bk,  Kb,  1.0f,   0 };
    GJob jv  = { WvB,  bv,  Vb,  1.0f,   0 };
    GJob jrq = { RWqB, Rbq, Qrb, 0.125f, 1 };
    GJob jrk = { RWkB, Rbk, Krb, 1.0f,   1 };
    k_gemm256<false><<<dim3(640), dim3(512), 0, stream>>>(hsB, jq, jk, jv, jrq, jrk, rt);

    k_vtrans<<<dim3(NB * NH * 16), dim3(256), 0, stream>>>(Vb, Vtb);
    k_attn<<<dim3(NB * NH * 8), dim3(512), 0, stream>>>(Qb, Kb, Qrb, Krb, Vtb, atb);

    GJob jo = { WoB, bo, d_out, 1.0f, 0 };
    k_gemm256<true><<<dim3(128), dim3(512), 0, stream>>>(atb, jo, jo, jo, jo, jo, nullptr);
}